// Round 20
// baseline (227.311 us; speedup 1.0000x reference)
//
#include <hip/hip_runtime.h>
#include <hip/hip_bf16.h>
#include <math.h>

#define TPB 256

typedef __attribute__((ext_vector_type(8))) short bf16x8_t;
typedef __attribute__((ext_vector_type(4))) float f32x4_t;
typedef __attribute__((ext_vector_type(4))) int i32x4_t;
typedef __attribute__((ext_vector_type(4))) unsigned short u16x4_t;
typedef __attribute__((ext_vector_type(8))) unsigned short u16x8_t;

#if defined(__has_builtin)
#if __has_builtin(__builtin_amdgcn_global_load_lds)
#define HAS_GLOAD_LDS 1
#endif
#endif

static __device__ __forceinline__ float bf16_to_f(unsigned short s) {
    union { unsigned u; float f; } cv;
    cv.u = ((unsigned)s) << 16;
    return cv.f;
}
static __device__ __forceinline__ short f_to_bf16(float v) {
    __hip_bfloat16 h = __float2bfloat16(v);
    return *(short*)&h;
}

// ------------------------------------------------- prep: x NCHW -> x4 NHWC4 bf16 + pool
__global__ void prep_kernel(const float* __restrict__ in,
                            unsigned short* __restrict__ x4,
                            float* __restrict__ pool)
{
    const int HWo = 25600, H = 640, W = 640;
    int idx = blockIdx.x * TPB + threadIdx.x;
    if (idx >= 8 * HWo) return;
    int b = idx / HWo, r = idx % HWo;
    int ho = r / 160, wo = r % 160;
    float s0 = 0.f, s1 = 0.f, s2 = 0.f;
    unsigned short* x4b = x4 + (size_t)b * H * W * 4;
#pragma unroll
    for (int dy = 0; dy < 4; ++dy) {
        int row = ho * 4 + dy;
        size_t base = ((size_t)row * W + wo * 4);
        f32x4_t a0 = *(const f32x4_t*)&in[((size_t)(b * 3 + 0) * H * W) + base];
        f32x4_t a1 = *(const f32x4_t*)&in[((size_t)(b * 3 + 1) * H * W) + base];
        f32x4_t a2 = *(const f32x4_t*)&in[((size_t)(b * 3 + 2) * H * W) + base];
        s0 += a0[0] + a0[1] + a0[2] + a0[3];
        s1 += a1[0] + a1[1] + a1[2] + a1[3];
        s2 += a2[0] + a2[1] + a2[2] + a2[3];
#pragma unroll
        for (int dx = 0; dx < 4; ++dx) {
            u16x4_t v;
            v[0] = (unsigned short)f_to_bf16(a0[dx]);
            v[1] = (unsigned short)f_to_bf16(a1[dx]);
            v[2] = (unsigned short)f_to_bf16(a2[dx]);
            v[3] = 0;
            *(u16x4_t*)&x4b[(base + dx) * 4] = v;
        }
    }
    pool[((size_t)(b * 3 + 0)) * HWo + r] = s0 * (1.0f / 16.0f);
    pool[((size_t)(b * 3 + 1)) * HWo + r] = s1 * (1.0f / 16.0f);
    pool[((size_t)(b * 3 + 2)) * HWo + r] = s2 * (1.0f / 16.0f);
}

// ------------------------------------------------- single repack-everything kernel
static __device__ __forceinline__ void repack_one(
    const float* __restrict__ w, short* __restrict__ wtf,
    int idx, int Oreal, int NFRAG)
{
    int j    = idx & 7;
    int lane = (idx >> 3) & 63;
    int t    = idx >> 9;
    int ocf  = t % NFRAG;
    int kc   = t / NFRAG;
    int oc   = ocf * 16 + (lane & 15);
    int tap  = kc >> 1;
    int ic   = (kc & 1) * 32 + (lane >> 4) * 8 + j;
    float v = 0.f;
    if (oc < Oreal)
        v = w[((size_t)(oc * 64 + ic)) * 9 + tap];
    wtf[idx] = f_to_bf16(v);
}

__global__ void repack_all_kernel(
    const float* __restrict__ w_bl1, short* __restrict__ wt1,
    const float* __restrict__ w_bl2, short* __restrict__ wt2,
    const float* __restrict__ w_d2,  short* __restrict__ wtd2,
    const float* __restrict__ w_d3,  short* __restrict__ wtd3,
    const float* __restrict__ w_off2, short* __restrict__ wtoff2,
    const float* __restrict__ w_off3, short* __restrict__ wtoff3,
    const float* __restrict__ w_d1,  short* __restrict__ wtd1,
    float* __restrict__ stats)
{
    int idx = blockIdx.x * TPB + threadIdx.x;
    if (idx < 36864) { repack_one(w_bl1, wt1, idx, 64, 4); return; }
    idx -= 36864;
    if (idx < 36864) { repack_one(w_bl2, wt2, idx, 64, 4); return; }
    idx -= 36864;
    if (idx < 36864) { repack_one(w_d2, wtd2, idx, 64, 4); return; }
    idx -= 36864;
    if (idx < 147456) { repack_one(w_d3, wtd3, idx, 256, 16); return; }
    idx -= 147456;
    if (idx < 18432) { repack_one(w_off2, wtoff2, idx, 18, 2); return; }
    idx -= 18432;
    if (idx < 18432) { repack_one(w_off3, wtoff3, idx, 18, 2); return; }
    idx -= 18432;
    if (idx < 2048) {
        int j = idx & 7, lane = (idx >> 3) & 63, ocf = idx >> 9;
        int oc = ocf * 16 + (lane & 15);
        int k  = (lane >> 4) * 8 + j;
        float v = 0.f;
        if (k < 27) v = w_d1[(size_t)oc * 27 + k];
        wtd1[idx] = f_to_bf16(v);
        return;
    }
    idx -= 2048;
    if (idx < 2560) stats[idx] = 0.f;
}

// ------------------------------------------------- MFMA conv 3x3 (64->64, s1)
template <int NORM>
__global__ __launch_bounds__(256, 3) void conv3x3_mfma_kernel(
    const short* __restrict__ xh,
    const short* __restrict__ wt,
    short* __restrict__ outh,
    float* __restrict__ stats,
    const float* __restrict__ stats_in,
    float invN,
    const float* __restrict__ zp)
{
    __shared__ short tile[2816 * 8];
    __shared__ float sstat[128];
    __shared__ float sm[64], sr[64];
    const int H = 160, W = 160, HW = 25600;
    int blk = blockIdx.x;
    int b  = blk / 100;
    int r  = blk % 100;
    int y0 = (r / 10) * 16;
    int x0 = (r % 10) * 16;
    const int tid = threadIdx.x;
    const short* inb = xh + (size_t)b * HW * 64;

    if (tid < 128) sstat[tid] = 0.f;
    if (NORM) {
        if (tid < 64) {
            float s = 0.f, s2 = 0.f;
#pragma unroll
            for (int k = 0; k < 8; ++k) {
                s  += stats_in[k * 128 + tid];
                s2 += stats_in[k * 128 + 64 + tid];
            }
            float mean = s * invN;
            float var  = s2 * invN - mean * mean;
            sm[tid] = mean;
            sr[tid] = rsqrtf(var + 1e-5f);
        }
        __syncthreads();
    }

    if (NORM == 0) {
#ifdef HAS_GLOAD_LDS
#pragma unroll
        for (int it = 0; it < 11; ++it) {
            int item = it * 256 + tid;
            int c8  = item & 7;
            int pix = item >> 3;
            int row = pix / 18;
            int col = pix - row * 18;
            int y = y0 + row - 1;
            int x = x0 + col - 1;
            bool ok = (pix < 324) & (y >= 0) & (y < H) & (x >= 0) & (x < W);
            int cs = c8 ^ (col & 7);
            const short* src = ok
                ? &inb[((size_t)y * W + x) * 64 + (cs << 3)]
                : (const short*)zp;
            __builtin_amdgcn_global_load_lds(
                (const __attribute__((address_space(1))) unsigned int*)src,
                (__attribute__((address_space(3))) unsigned int*)
                    &tile[(it * 256 + (tid & 192)) * 8],
                16, 0, 0);
        }
#else
#pragma unroll
        for (int it = 0; it < 11; ++it) {
            int item = it * 256 + tid;
            int c8  = item & 7;
            int pix = item >> 3;
            int row = pix / 18;
            int col = pix - row * 18;
            int y = y0 + row - 1;
            int x = x0 + col - 1;
            bool ok = (pix < 324) & (y >= 0) & (y < H) & (x >= 0) & (x < W);
            int cs = c8 ^ (col & 7);
            const short* src = ok
                ? &inb[((size_t)y * W + x) * 64 + (cs << 3)]
                : (const short*)zp;
            *(bf16x8_t*)&tile[item * 8] = *(const bf16x8_t*)src;
        }
#endif
    } else {
#pragma unroll
        for (int it = 0; it < 11; ++it) {
            int item = it * 256 + tid;
            int c8  = item & 7;
            int pix = item >> 3;
            int row = pix / 18;
            int col = pix - row * 18;
            int y = y0 + row - 1;
            int x = x0 + col - 1;
            bool ok = (pix < 324) & (y >= 0) & (y < H) & (x >= 0) & (x < W);
            int cs = c8 ^ (col & 7);
            const short* src = ok
                ? &inb[((size_t)y * W + x) * 64 + (cs << 3)]
                : (const short*)zp;
            bf16x8_t v = *(const bf16x8_t*)src;
            int cs8 = cs << 3;
            bf16x8_t o;
#pragma unroll
            for (int j = 0; j < 8; ++j) {
                float f = (bf16_to_f((unsigned short)v[j]) - sm[cs8 + j]) * sr[cs8 + j];
                f = f > 0.f ? f : 0.f;
                o[j] = ok ? f_to_bf16(f) : (short)0;
            }
            *(bf16x8_t*)&tile[item * 8] = o;
        }
    }
    __syncthreads();

    const int wv  = tid >> 6;
    const int l   = tid & 63;
    const int l15 = l & 15;
    const int lg  = l >> 4;

    f32x4_t acc[4][4];
#pragma unroll
    for (int i = 0; i < 4; ++i)
#pragma unroll
        for (int j = 0; j < 4; ++j)
            acc[i][j] = (f32x4_t){0.f, 0.f, 0.f, 0.f};

    bf16x8_t bfp[2][4], afp[2][4];
#pragma unroll
    for (int nf = 0; nf < 4; ++nf)
        bfp[0][nf] = *(const bf16x8_t*)(wt + (((size_t)(0 * 4 + nf)) * 64 + l) * 8);
    {
        int colr = l15;
        int chunk = lg ^ (colr & 7);
#pragma unroll
        for (int mf = 0; mf < 4; ++mf)
            afp[0][mf] = *(const bf16x8_t*)&tile[((wv * 4 + mf) * 18 + colr) * 64 + chunk * 8];
    }
#pragma unroll
    for (int kc = 0; kc < 18; ++kc) {
        const int cur = kc & 1, nxt = cur ^ 1;
        if (kc + 1 < 18) {
            int kn = kc + 1;
#pragma unroll
            for (int nf = 0; nf < 4; ++nf)
                bfp[nxt][nf] = *(const bf16x8_t*)(wt + (((size_t)(kn * 4 + nf)) * 64 + l) * 8);
            int tap = kn >> 1;
            int dy = tap / 3, dx = tap % 3;
            int colr = l15 + dx;
            int chunk = (((kn & 1) << 2) + lg) ^ (colr & 7);
#pragma unroll
            for (int mf = 0; mf < 4; ++mf)
                afp[nxt][mf] = *(const bf16x8_t*)&tile[((wv * 4 + mf + dy) * 18 + colr) * 64 + chunk * 8];
        }
#pragma unroll
        for (int mf = 0; mf < 4; ++mf)
#pragma unroll
            for (int nf = 0; nf < 4; ++nf)
                acc[mf][nf] = __builtin_amdgcn_mfma_f32_16x16x32_bf16(
                    afp[cur][mf], bfp[cur][nf], acc[mf][nf], 0, 0, 0);
    }

    __syncthreads();
#pragma unroll
    for (int mf = 0; mf < 4; ++mf) {
        int py = wv * 4 + mf;
#pragma unroll
        for (int nf = 0; nf < 4; ++nf) {
            int oc = nf * 16 + l15;
#pragma unroll
            for (int k = 0; k < 4; ++k)
                tile[((py * 16) + lg * 4 + k) * 64 + oc] = f_to_bf16(acc[mf][nf][k]);
        }
    }
    __syncthreads();
    short* outb = outh + (size_t)b * HW * 64;
#pragma unroll
    for (int j = 0; j < 8; ++j) {
        int item = j * 256 + tid;
        int c8  = item & 7;
        int pix = item >> 3;
        int py  = pix >> 4, px = pix & 15;
        *(bf16x8_t*)&outb[((size_t)(y0 + py) * W + x0 + px) * 64 + c8 * 8] =
            *(bf16x8_t*)&tile[pix * 64 + c8 * 8];
    }

#pragma unroll
    for (int nf = 0; nf < 4; ++nf) {
        float s = 0.f, s2 = 0.f;
#pragma unroll
        for (int mf = 0; mf < 4; ++mf)
#pragma unroll
            for (int k = 0; k < 4; ++k) {
                float v = acc[mf][nf][k];
                s += v; s2 += v * v;
            }
        s  += __shfl_xor(s, 16, 64);  s  += __shfl_xor(s, 32, 64);
        s2 += __shfl_xor(s2, 16, 64); s2 += __shfl_xor(s2, 32, 64);
        if (lg == 0) {
            int oc = nf * 16 + l15;
            atomicAdd(&sstat[oc], s);
            atomicAdd(&sstat[64 + oc], s2);
        }
    }
    __syncthreads();
    float* st = stats + (size_t)(blockIdx.x & 7) * 128;
    if (tid < 128) atomicAdd(&st[tid], sstat[tid]);
}

// ------------------------------------------------- BN apply dual
__global__ __launch_bounds__(256, 2) void bn_apply_dual_kernel(
    const short* __restrict__ in,
    const float* __restrict__ stats,
    float* __restrict__ out,
    short* __restrict__ outh,
    int HW, float invN)
{
    __shared__ float ftile[64][65];
    __shared__ float sm[64], sr[64];
    int nchunks = HW >> 6;
    int b  = blockIdx.x / nchunks;
    int p0 = (blockIdx.x % nchunks) << 6;
    int tid = threadIdx.x;
    if (tid < 64) {
        float s = 0.f, s2 = 0.f;
#pragma unroll
        for (int k = 0; k < 8; ++k) {
            s  += stats[k * 128 + tid];
            s2 += stats[k * 128 + 64 + tid];
        }
        float mean = s * invN;
        float var  = s2 * invN - mean * mean;
        sm[tid] = mean;
        sr[tid] = rsqrtf(var + 1e-5f);
    }
    __syncthreads();
#pragma unroll
    for (int it = 0; it < 2; ++it) {
        int item = it * 256 + tid;
        int p = item >> 3, c0 = (item & 7) * 8;
        size_t gi = ((size_t)(b * HW + p0 + p)) * 64 + c0;
        bf16x8_t v = *(const bf16x8_t*)&in[gi];
        bf16x8_t o;
#pragma unroll
        for (int j = 0; j < 8; ++j) {
            float f = (bf16_to_f((unsigned short)v[j]) - sm[c0 + j]) * sr[c0 + j];
            f = f > 0.f ? f : 0.f;
            ftile[p][c0 + j] = f;
            o[j] = f_to_bf16(f);
        }
        *(bf16x8_t*)&outh[gi] = o;
    }
    __syncthreads();
#pragma unroll
    for (int rep = 0; rep < 16; ++rep) {
        int item = rep * 256 + tid;
        int c = item >> 6, p = item & 63;
        out[((size_t)b * 64 + c) * HW + p0 + p] = ftile[p][c];
    }
}

// ------------------------------------------------- offset2/3: MFMA conv, N=18
__global__ __launch_bounds__(256, 2) void offconv_mfma_kernel(
    const short* __restrict__ xh,
    const short* __restrict__ wt,
    const float* __restrict__ bias,
    float* __restrict__ out,
    int H, int W, int Ho, int Wo)
{
    const int HW = Ho * Wo;
    const int tid = threadIdx.x;
    const int wv = tid >> 6, l = tid & 63;
    const int l15 = l & 15, lg = l >> 4;
    const int pix0 = blockIdx.x * 64 + wv * 16;
    const int b = pix0 / HW;
    const int r0 = pix0 - b * HW;

    int rp = r0 + l15;
    int ho = rp / Wo, wo = rp % Wo;
    const short* xb = xh + (size_t)b * H * W * 64;

    f32x4_t acc[2];
    acc[0] = (f32x4_t){0.f, 0.f, 0.f, 0.f};
    acc[1] = (f32x4_t){0.f, 0.f, 0.f, 0.f};

#pragma unroll 2
    for (int kc = 0; kc < 18; ++kc) {
        int tap = kc >> 1;
        int iy = ho * 2 - 1 + tap / 3;
        int ix = wo * 2 - 1 + tap % 3;
        bf16x8_t af = {};
        if (iy >= 0 && iy < H && ix >= 0 && ix < W)
            af = *(const bf16x8_t*)&xb[((size_t)iy * W + ix) * 64
                                       + (kc & 1) * 32 + lg * 8];
#pragma unroll
        for (int nf = 0; nf < 2; ++nf) {
            bf16x8_t bf = *(const bf16x8_t*)(wt + (((size_t)(kc * 2 + nf)) * 64 + l) * 8);
            acc[nf] = __builtin_amdgcn_mfma_f32_16x16x32_bf16(af, bf, acc[nf], 0, 0, 0);
        }
    }

#pragma unroll
    for (int nf = 0; nf < 2; ++nf) {
        int oc = nf * 16 + l15;
        if (oc < 18) {
            float bv = bias[oc];
            f32x4_t v = acc[nf];
            v[0] += bv; v[1] += bv; v[2] += bv; v[3] += bv;
            *(f32x4_t*)&out[((size_t)(b * 18 + oc)) * HW + r0 + lg * 4] = v;
        }
    }
}

// ------------------------------------------------- deform1: fused offset1 +
// deform (C=3, MFMA MAC) + skip; x4 is bf16 NHWC4
__global__ __launch_bounds__(256, 2) void deform1_kernel(
    const unsigned short* __restrict__ x4,
    const float* __restrict__ wof,
    const float* __restrict__ bof,
    const short* __restrict__ wtd1,
    const float* __restrict__ bias,
    const float* __restrict__ pool,
    const float* __restrict__ wsk,
    const float* __restrict__ bsk,
    short* __restrict__ outh)
{
    const int H = 640, W = 640, Ho = 160, Wo = 160, HW = 25600;
    constexpr int P = 32;
    __shared__ float xtap[P * 9][4];
    __shared__ float swof[486];
    __shared__ float sbof[18];
    __shared__ float spool[3][P];
    __shared__ float off1[P][18];
    __shared__ alignas(16) short sampb[P][40];
    __shared__ int   sidx[P * 9][4];
    __shared__ float swt[P * 9][4];
    const int tid = threadIdx.x;
    const int pix0 = blockIdx.x * P;
    const int b = pix0 / HW;
    const int r0 = pix0 - b * HW;
    const unsigned short* xb = x4 + (size_t)b * H * W * 4;

    for (int item = tid; item < P * 9; item += TPB) {
        int p = item / 9, tap = item % 9;
        int r = r0 + p, ho = r / Wo, wo = r % Wo;
        int iy = ho * 4 - 1 + tap / 3;
        int ix = wo * 4 - 1 + tap % 3;
        f32x4_t s = (f32x4_t){0.f, 0.f, 0.f, 0.f};
        if (iy >= 0 && iy < H && ix >= 0 && ix < W) {
            u16x4_t u = *(const u16x4_t*)&xb[((size_t)iy * W + ix) * 4];
            s[0] = bf16_to_f(u[0]);
            s[1] = bf16_to_f(u[1]);
            s[2] = bf16_to_f(u[2]);
        }
        *(f32x4_t*)xtap[item] = s;
    }
    for (int i = tid; i < P * 40; i += TPB) ((short*)sampb)[i] = 0;
    for (int i = tid; i < 96; i += TPB) {
        int c = i >> 5, p = i & 31;
        spool[c][p] = pool[((size_t)(b * 3 + c)) * HW + r0 + p];
    }
    for (int item = tid; item < 486; item += TPB) swof[item] = wof[item];
    if (tid < 18) sbof[tid] = bof[tid];
    __syncthreads();

    for (int item = tid; item < P * 18; item += TPB) {
        int p = item / 18, o = item % 18;
        float acc = sbof[o];
#pragma unroll
        for (int tap = 0; tap < 9; ++tap) {
            const float* xt = xtap[p * 9 + tap];
#pragma unroll
            for (int c = 0; c < 3; ++c)
                acc += xt[c] * swof[(o * 3 + c) * 9 + tap];
        }
        off1[p][o] = acc;
    }
    __syncthreads();

    for (int item = tid; item < P * 9; item += TPB) {
        int p = item / 9, tap = item % 9;
        int r = r0 + p, ho = r / Wo, wo = r % Wo;
        float dy = off1[p][2 * tap];
        float dx = off1[p][2 * tap + 1];
        float ys = (float)(ho * 4 - 1 + tap / 3) + dy;
        float xs = (float)(wo * 4 - 1 + tap % 3) + dx;
        float y0f = floorf(ys), x0f = floorf(xs);
        float fy = ys - y0f, fx = xs - x0f;
        int y0 = (int)y0f, x0 = (int)x0f;
        float wts[4] = {(1.f - fy) * (1.f - fx), (1.f - fy) * fx,
                        fy * (1.f - fx),          fy * fx};
#pragma unroll
        for (int j = 0; j < 4; ++j) {
            int iy = y0 + (j >> 1), ix = x0 + (j & 1);
            bool v = (iy >= 0) && (iy < H) && (ix >= 0) && (ix < W);
            sidx[item][j] = v ? (iy * W + ix) : 0;
            swt[item][j]  = v ? wts[j] : 0.f;
        }
    }
    __syncthreads();

    for (int item = tid; item < P * 9; item += TPB) {
        int p = item / 9, tap = item % 9;
        i32x4_t id4 = *(const i32x4_t*)sidx[item];
        f32x4_t w4  = *(const f32x4_t*)swt[item];
        u16x4_t a0 = *(const u16x4_t*)&xb[(size_t)(unsigned)id4[0] * 4];
        u16x4_t a1 = *(const u16x4_t*)&xb[(size_t)(unsigned)id4[1] * 4];
        u16x4_t a2 = *(const u16x4_t*)&xb[(size_t)(unsigned)id4[2] * 4];
        u16x4_t a3 = *(const u16x4_t*)&xb[(size_t)(unsigned)id4[3] * 4];
        sampb[p][0 * 9 + tap] = f_to_bf16(
            w4[0]*bf16_to_f(a0[0]) + w4[1]*bf16_to_f(a1[0])
          + w4[2]*bf16_to_f(a2[0]) + w4[3]*bf16_to_f(a3[0]));
        sampb[p][1 * 9 + tap] = f_to_bf16(
            w4[0]*bf16_to_f(a0[1]) + w4[1]*bf16_to_f(a1[1])
          + w4[2]*bf16_to_f(a2[1]) + w4[3]*bf16_to_f(a3[1]));
        sampb[p][2 * 9 + tap] = f_to_bf16(
            w4[0]*bf16_to_f(a0[2]) + w4[1]*bf16_to_f(a1[2])
          + w4[2]*bf16_to_f(a2[2]) + w4[3]*bf16_to_f(a3[2]));
    }
    __syncthreads();

    const int wv = tid >> 6;
    const int l  = tid & 63;
    const int l15 = l & 15, lg = l >> 4;
    bf16x8_t bf  = *(const bf16x8_t*)(wtd1 + (((size_t)wv * 64 + l)) * 8);
    bf16x8_t af0 = *(const bf16x8_t*)&sampb[l15][lg * 8];
    bf16x8_t af1 = *(const bf16x8_t*)&sampb[l15 + 16][lg * 8];
    f32x4_t z = (f32x4_t){0.f, 0.f, 0.f, 0.f};
    f32x4_t acc0 = __builtin_amdgcn_mfma_f32_16x16x32_bf16(af0, bf, z, 0, 0, 0);
    f32x4_t acc1 = __builtin_amdgcn_mfma_f32_16x16x32_bf16(af1, bf, z, 0, 0, 0);

    int oc = wv * 16 + l15;
    float bb = bias[oc] + bsk[oc];
    float w0 = wsk[oc * 3 + 0], w1 = wsk[oc * 3 + 1], w2 = wsk[oc * 3 + 2];
    short* otile = (short*)xtap;
    __syncthreads();
#pragma unroll
    for (int mf = 0; mf < 2; ++mf) {
        f32x4_t a = mf ? acc1 : acc0;
#pragma unroll
        for (int k = 0; k < 4; ++k) {
            int px = mf * 16 + lg * 4 + k;
            float sv = w0 * spool[0][px] + w1 * spool[1][px] + w2 * spool[2][px];
            otile[px * 64 + oc] = f_to_bf16(a[k] + bb + sv);
        }
    }
    __syncthreads();
    {
        int c8 = tid & 7, px = tid >> 3;
        *(bf16x8_t*)&outh[((size_t)(b * HW + r0 + px)) * 64 + c8 * 8] =
            *(bf16x8_t*)&otile[px * 64 + c8 * 8];
    }
}

// ------------------------------------------------- deform MFMA: C=64 -> O
template <int O, int DUAL>
__global__ __launch_bounds__(256, 2) void deform_mfma_kernel(
    const short* __restrict__ xh,
    const float* __restrict__ off,
    const short* __restrict__ wt,
    const float* __restrict__ bias,
    float* __restrict__ out,
    short* __restrict__ outh,
    int H, int W, int Ho, int Wo, int stride)
{
    constexpr int NF = O / 64;
    constexpr int NFRAG = O / 16;
    constexpr int P  = 32;
    __shared__ alignas(16) short samp[P * 576];
    __shared__ int   sidx[P * 9][4];
    __shared__ float swt[P * 9][4];

    const int tid = threadIdx.x;
    const int HW = Ho * Wo;
    const int pix0 = blockIdx.x * P;
    const int b = pix0 / HW;
    const int r0 = pix0 - b * HW;

    for (int item = tid; item < P * 9; item += TPB) {
        int p = item / 9, tap = item % 9;
        int r = r0 + p, ho = r / Wo, wo = r % Wo;
        float dy = off[((size_t)(b * 18 + 2 * tap) * Ho + ho) * Wo + wo];
        float dx = off[((size_t)(b * 18 + 2 * tap + 1) * Ho + ho) * Wo + wo];
        float ys = (float)(ho * stride - 1 + tap / 3) + dy;
        float xs = (float)(wo * stride - 1 + tap % 3) + dx;
        float y0f = floorf(ys), x0f = floorf(xs);
        float fy = ys - y0f, fx = xs - x0f;
        int y0 = (int)y0f, x0 = (int)x0f;
        float wts[4] = {(1.f - fy) * (1.f - fx), (1.f - fy) * fx,
                        fy * (1.f - fx),          fy * fx};
#pragma unroll
        for (int j = 0; j < 4; ++j) {
            int iy = y0 + (j >> 1), ix = x0 + (j & 1);
            bool v = (iy >= 0) && (iy < H) && (ix >= 0) && (ix < W);
            sidx[item][j] = v ? (iy * W + ix) : 0;
            swt[item][j]  = v ? wts[j] : 0.f;
        }
    }
    __syncthreads();

    {
        const int p  = tid >> 3;
        const int ic = (tid & 7) * 8;
        const int swc = (ic >> 3) ^ (p & 7);
        const short* xb = xh + (size_t)b * H * W * 64;
#pragma unroll 3
        for (int tap = 0; tap < 9; ++tap) {
            int e = p * 9 + tap;
            i32x4_t id4 = *(const i32x4_t*)sidx[e];
            f32x4_t w4  = *(const f32x4_t*)swt[e];
            u16x8_t u0 = *(const u16x8_t*)&xb[(size_t)(unsigned)id4[0] * 64 + ic];
            u16x8_t u1 = *(const u16x8_t*)&xb[(size_t)(unsigned)id4[1] * 64 + ic];
            u16x8_t u2 = *(const u16x8_t*)&xb[(size_t)(unsigned)id4[2] * 64 + ic];
            u16x8_t u3 = *(const u16x8_t*)&xb[(size_t)(unsigned)id4[3] * 64 + ic];
            bf16x8_t o;
#pragma unroll
            for (int j = 0; j < 8; ++j) {
                float v = w4[0]*bf16_to_f(u0[j]) + w4[1]*bf16_to_f(u1[j])
                        + w4[2]*bf16_to_f(u2[j]) + w4[3]*bf16_to_f(u3[j]);
                o[j] = f_to_bf16(v);
            }
            *(bf16x8_t*)&samp[p * 576 + (tap * 8 + swc) * 8] = o;
        }
    }
    __syncthreads();

    const int wv = tid >> 6;
    const int l  = tid & 63;
    const int l15 = l & 15, lg = l >> 4;
    f32x4_t acc[2][NF];
#pragma unroll
    for (int mf = 0; mf < 2; ++mf)
#pragma unroll
        for (int nf = 0; nf < NF; ++nf)
            acc[mf][nf] = (f32x4_t){0.f, 0.f, 0.f, 0.f};

#pragma unroll 2
    for (int kc = 0; kc < 18; ++kc) {
        int tap = kc >> 1;
        int low = (((kc & 1) << 2) | lg) ^ (l15 & 7);
        bf16x8_t af0 = *(const bf16x8_t*)&samp[l15 * 576 + (tap * 8 + low) * 8];
        bf16x8_t af1 = *(const bf16x8_t*)&samp[(l15 + 16) * 576 + (tap * 8 + low) * 8];
#pragma unroll
        for (int nf = 0; nf < NF; ++nf) {
            int ocf = wv * NF + nf;
            bf16x8_t bf = *(const bf16x8_t*)(wt + (((size_t)(kc * NFRAG + ocf)) * 64 + l) * 8);
            acc[0][nf] = __builtin_amdgcn_mfma_f32_16x16x32_bf16(af0, bf, acc[0][nf], 0, 0, 0);
            acc[1][nf] = __builtin_amdgcn_mfma_f32_16x16x32_bf16(af1, bf, acc[1][nf], 0, 0, 0);
        }
    }

#pragma unroll
    for (int mf = 0; mf < 2; ++mf)
#pragma unroll
        for (int nf = 0; nf < NF; ++nf) {
            int oc = (wv * NF + nf) * 16 + l15;
            float bv = bias[oc];
            f32x4_t v = acc[mf][nf];
            v[0] += bv; v[1] += bv; v[2] += bv; v[3] += bv;
            acc[mf][nf] = v;
            *(f32x4_t*)&out[((size_t)(b * O + oc)) * HW + r0 + mf * 16 + lg * 4] = v;
        }

    if (DUAL) {
        __syncthreads();
        short* otile = samp;
#pragma unroll
        for (int mf = 0; mf < 2; ++mf) {
            int oc = wv * 16 + l15;
#pragma unroll
            for (int k = 0; k < 4; ++k) {
                int px = mf * 16 + lg * 4 + k;
                otile[px * 64 + oc] = f_to_bf16(acc[mf][0][k]);
            }
        }
        __syncthreads();
        int c8 = tid & 7, px = tid >> 3;
        *(bf16x8_t*)&outh[((size_t)(b * HW + r0 + px)) * 64 + c8 * 8] =
            *(bf16x8_t*)&otile[px * 64 + c8 * 8];
    }
}

// ---------------------------------------------------------------- launch
extern "C" void kernel_launch(void* const* d_in, const int* in_sizes, int n_in,
                              void* d_out, int out_size, void* d_ws, size_t ws_size,
                              hipStream_t stream)
{
    const float* x      = (const float*)d_in[0];
    const float* w_off1 = (const float*)d_in[1];
    const float* b_off1 = (const float*)d_in[2];
    const float* w_d1   = (const float*)d_in[3];
    const float* b_d1   = (const float*)d_in[4];
    const float* w_skip = (const float*)d_in[5];
    const float* b_skip = (const float*)d_in[6];
    const float* w_bl1  = (const float*)d_in[7];
    const float* w_bl2  = (const float*)d_in[8];
    const float* w_off2 = (const float*)d_in[9];
    const float* b_off2 = (const float*)d_in[10];
    const float* w_d2   = (const float*)d_in[11];
    const float* b_d2   = (const float*)d_in[12];
    const float* w_off3 = (const float*)d_in[13];
    const float* b_off3 = (const float*)d_in[14];
    const float* w_d3   = (const float*)d_in[15];
    const float* b_d3   = (const float*)d_in[16];

    const int B = 8;
    float* A     = (float*)d_ws;
    float* bufB  = A + 3686400;
    float* bufC  = bufB + 13107200;

    short* hB   = (short*)bufB;
    short* hC   = (short*)bufC;
    float* pool = bufB + 8000000;

    short* wt1    = (short*)(A + 1000000);
    short* wt2    = wt1 + 18 * 4 * 512;
    short* wtd2   = (short*)(A + 1500000);
    short* wtd3   = (short*)(A + 1550000);
    short* wtoff2 = (short*)(A + 1700000);
    short* wtoff3 = (short*)(A + 1712000);
    short* wtd1   = (short*)(A + 1750000);
    float* stats1 = A + 1800000;
    float* stats2 = stats1 + 1024;
    float* zpage  = stats1 + 2048;

    float* out0 = (float*)d_out;
    float* out1 = out0 + 13107200;
    float* out2 = out1 + 3276800;

    const float invN = 1.0f / (B * 25600);

    prep_kernel<<<(8 * 25600 + TPB - 1) / TPB, TPB, 0, stream>>>(
        x, (unsigned short*)bufC, pool);

    repack_all_kernel<<<(299520 + TPB - 1) / TPB, TPB, 0, stream>>>(
        w_bl1, wt1, w_bl2, wt2, w_d2, wtd2, w_d3, wtd3,
        w_off2, wtoff2, w_off3, wtoff3, w_d1, wtd1, stats1);

    deform1_kernel<<<8 * 25600 / 32, TPB, 0, stream>>>(
        (const unsigned short*)bufC, w_off1, b_off1, wtd1, b_d1,
        pool, w_skip, b_skip, hB);

    conv3x3_mfma_kernel<0><<<800, TPB, 0, stream>>>(
        hB, wt1, hC, stats1, nullptr, invN, zpage);

    conv3x3_mfma_kernel<1><<<800, TPB, 0, stream>>>(
        hC, wt2, hB, stats2, stats1, invN, zpage);

    bn_apply_dual_kernel<<<8 * 400, TPB, 0, stream>>>(
        hB, stats2, out0, hC, 25600, invN);

    offconv_mfma_kernel<<<8 * 6400 / 64, TPB, 0, stream>>>(
        hC, wtoff2, b_off2, A, 160, 160, 80, 80);

    deform_mfma_kernel<64, 1><<<8 * 6400 / 32, TPB, 0, stream>>>(
        hC, A, wtd2, b_d2, out1, hB, 160, 160, 80, 80, 2);

    offconv_mfma_kernel<<<8 * 1600 / 64, TPB, 0, stream>>>(
        hB, wtoff3, b_off3, A, 80, 80, 40, 40);

    deform_mfma_kernel<256, 0><<<8 * 1600 / 32, TPB, 0, stream>>>(
        hB, A, wtd3, b_d3, out2, nullptr, 80, 80, 40, 40, 2);
}

// Round 21
// 205.704 us; speedup vs baseline: 1.1050x; 1.1050x over previous
//
#include <hip/hip_runtime.h>
#include <hip/hip_bf16.h>
#include <math.h>

#define TPB 256

typedef __attribute__((ext_vector_type(8))) short bf16x8_t;
typedef __attribute__((ext_vector_type(4))) float f32x4_t;
typedef __attribute__((ext_vector_type(4))) int i32x4_t;
typedef __attribute__((ext_vector_type(4))) unsigned short u16x4_t;
typedef __attribute__((ext_vector_type(8))) unsigned short u16x8_t;

#if defined(__has_builtin)
#if __has_builtin(__builtin_amdgcn_global_load_lds)
#define HAS_GLOAD_LDS 1
#endif
#endif

static __device__ __forceinline__ float bf16_to_f(unsigned short s) {
    union { unsigned u; float f; } cv;
    cv.u = ((unsigned)s) << 16;
    return cv.f;
}
static __device__ __forceinline__ short f_to_bf16(float v) {
    __hip_bfloat16 h = __float2bfloat16(v);
    return *(short*)&h;
}

// ------------------------------------------------- prep: x NCHW -> x4 NHWC4 bf16 + pool
__global__ void prep_kernel(const float* __restrict__ in,
                            unsigned short* __restrict__ x4,
                            float* __restrict__ pool)
{
    const int HWo = 25600, H = 640, W = 640;
    int idx = blockIdx.x * TPB + threadIdx.x;
    if (idx >= 8 * HWo) return;
    int b = idx / HWo, r = idx % HWo;
    int ho = r / 160, wo = r % 160;
    float s0 = 0.f, s1 = 0.f, s2 = 0.f;
    unsigned short* x4b = x4 + (size_t)b * H * W * 4;
#pragma unroll
    for (int dy = 0; dy < 4; ++dy) {
        int row = ho * 4 + dy;
        size_t base = ((size_t)row * W + wo * 4);
        f32x4_t a0 = *(const f32x4_t*)&in[((size_t)(b * 3 + 0) * H * W) + base];
        f32x4_t a1 = *(const f32x4_t*)&in[((size_t)(b * 3 + 1) * H * W) + base];
        f32x4_t a2 = *(const f32x4_t*)&in[((size_t)(b * 3 + 2) * H * W) + base];
        s0 += a0[0] + a0[1] + a0[2] + a0[3];
        s1 += a1[0] + a1[1] + a1[2] + a1[3];
        s2 += a2[0] + a2[1] + a2[2] + a2[3];
#pragma unroll
        for (int dx = 0; dx < 4; ++dx) {
            u16x4_t v;
            v[0] = (unsigned short)f_to_bf16(a0[dx]);
            v[1] = (unsigned short)f_to_bf16(a1[dx]);
            v[2] = (unsigned short)f_to_bf16(a2[dx]);
            v[3] = 0;
            *(u16x4_t*)&x4b[(base + dx) * 4] = v;
        }
    }
    pool[((size_t)(b * 3 + 0)) * HWo + r] = s0 * (1.0f / 16.0f);
    pool[((size_t)(b * 3 + 1)) * HWo + r] = s1 * (1.0f / 16.0f);
    pool[((size_t)(b * 3 + 2)) * HWo + r] = s2 * (1.0f / 16.0f);
}

// ------------------------------------------------- single repack-everything kernel
static __device__ __forceinline__ void repack_one(
    const float* __restrict__ w, short* __restrict__ wtf,
    int idx, int Oreal, int NFRAG)
{
    int j    = idx & 7;
    int lane = (idx >> 3) & 63;
    int t    = idx >> 9;
    int ocf  = t % NFRAG;
    int kc   = t / NFRAG;
    int oc   = ocf * 16 + (lane & 15);
    int tap  = kc >> 1;
    int ic   = (kc & 1) * 32 + (lane >> 4) * 8 + j;
    float v = 0.f;
    if (oc < Oreal)
        v = w[((size_t)(oc * 64 + ic)) * 9 + tap];
    wtf[idx] = f_to_bf16(v);
}

__global__ void repack_all_kernel(
    const float* __restrict__ w_bl1, short* __restrict__ wt1,
    const float* __restrict__ w_bl2, short* __restrict__ wt2,
    const float* __restrict__ w_d2,  short* __restrict__ wtd2,
    const float* __restrict__ w_d3,  short* __restrict__ wtd3,
    const float* __restrict__ w_off2, short* __restrict__ wtoff2,
    const float* __restrict__ w_off3, short* __restrict__ wtoff3,
    const float* __restrict__ w_d1,  short* __restrict__ wtd1,
    float* __restrict__ stats)
{
    int idx = blockIdx.x * TPB + threadIdx.x;
    if (idx < 36864) { repack_one(w_bl1, wt1, idx, 64, 4); return; }
    idx -= 36864;
    if (idx < 36864) { repack_one(w_bl2, wt2, idx, 64, 4); return; }
    idx -= 36864;
    if (idx < 36864) { repack_one(w_d2, wtd2, idx, 64, 4); return; }
    idx -= 36864;
    if (idx < 147456) { repack_one(w_d3, wtd3, idx, 256, 16); return; }
    idx -= 147456;
    if (idx < 18432) { repack_one(w_off2, wtoff2, idx, 18, 2); return; }
    idx -= 18432;
    if (idx < 18432) { repack_one(w_off3, wtoff3, idx, 18, 2); return; }
    idx -= 18432;
    if (idx < 2048) {
        int j = idx & 7, lane = (idx >> 3) & 63, ocf = idx >> 9;
        int oc = ocf * 16 + (lane & 15);
        int k  = (lane >> 4) * 8 + j;
        float v = 0.f;
        if (k < 27) v = w_d1[(size_t)oc * 27 + k];
        wtd1[idx] = f_to_bf16(v);
        return;
    }
    idx -= 2048;
    if (idx < 2560) stats[idx] = 0.f;
}

// ------------------------------------------------- MFMA conv 3x3 (64->64, s1)
template <int NORM>
__global__ __launch_bounds__(256, 2) void conv3x3_mfma_kernel(
    const short* __restrict__ xh,
    const short* __restrict__ wt,
    short* __restrict__ outh,
    float* __restrict__ stats,
    const float* __restrict__ stats_in,
    float invN,
    const float* __restrict__ zp)
{
    __shared__ short tile[2816 * 8];
    __shared__ float sstat[128];
    __shared__ float sm[64], sr[64];
    const int H = 160, W = 160, HW = 25600;
    int blk = blockIdx.x;
    int b  = blk / 100;
    int r  = blk % 100;
    int y0 = (r / 10) * 16;
    int x0 = (r % 10) * 16;
    const int tid = threadIdx.x;
    const short* inb = xh + (size_t)b * HW * 64;

    if (tid < 128) sstat[tid] = 0.f;
    if (NORM) {
        if (tid < 64) {
            float s = 0.f, s2 = 0.f;
#pragma unroll
            for (int k = 0; k < 8; ++k) {
                s  += stats_in[k * 128 + tid];
                s2 += stats_in[k * 128 + 64 + tid];
            }
            float mean = s * invN;
            float var  = s2 * invN - mean * mean;
            sm[tid] = mean;
            sr[tid] = rsqrtf(var + 1e-5f);
        }
        __syncthreads();
    }

    if (NORM == 0) {
#ifdef HAS_GLOAD_LDS
#pragma unroll
        for (int it = 0; it < 11; ++it) {
            int item = it * 256 + tid;
            int c8  = item & 7;
            int pix = item >> 3;
            int row = pix / 18;
            int col = pix - row * 18;
            int y = y0 + row - 1;
            int x = x0 + col - 1;
            bool ok = (pix < 324) & (y >= 0) & (y < H) & (x >= 0) & (x < W);
            int cs = c8 ^ (col & 7);
            const short* src = ok
                ? &inb[((size_t)y * W + x) * 64 + (cs << 3)]
                : (const short*)zp;
            __builtin_amdgcn_global_load_lds(
                (const __attribute__((address_space(1))) unsigned int*)src,
                (__attribute__((address_space(3))) unsigned int*)
                    &tile[(it * 256 + (tid & 192)) * 8],
                16, 0, 0);
        }
#else
#pragma unroll
        for (int it = 0; it < 11; ++it) {
            int item = it * 256 + tid;
            int c8  = item & 7;
            int pix = item >> 3;
            int row = pix / 18;
            int col = pix - row * 18;
            int y = y0 + row - 1;
            int x = x0 + col - 1;
            bool ok = (pix < 324) & (y >= 0) & (y < H) & (x >= 0) & (x < W);
            int cs = c8 ^ (col & 7);
            const short* src = ok
                ? &inb[((size_t)y * W + x) * 64 + (cs << 3)]
                : (const short*)zp;
            *(bf16x8_t*)&tile[item * 8] = *(const bf16x8_t*)src;
        }
#endif
    } else {
#pragma unroll
        for (int it = 0; it < 11; ++it) {
            int item = it * 256 + tid;
            int c8  = item & 7;
            int pix = item >> 3;
            int row = pix / 18;
            int col = pix - row * 18;
            int y = y0 + row - 1;
            int x = x0 + col - 1;
            bool ok = (pix < 324) & (y >= 0) & (y < H) & (x >= 0) & (x < W);
            int cs = c8 ^ (col & 7);
            const short* src = ok
                ? &inb[((size_t)y * W + x) * 64 + (cs << 3)]
                : (const short*)zp;
            bf16x8_t v = *(const bf16x8_t*)src;
            int cs8 = cs << 3;
            bf16x8_t o;
#pragma unroll
            for (int j = 0; j < 8; ++j) {
                float f = (bf16_to_f((unsigned short)v[j]) - sm[cs8 + j]) * sr[cs8 + j];
                f = f > 0.f ? f : 0.f;
                o[j] = ok ? f_to_bf16(f) : (short)0;
            }
            *(bf16x8_t*)&tile[item * 8] = o;
        }
    }
    __syncthreads();

    const int wv  = tid >> 6;
    const int l   = tid & 63;
    const int l15 = l & 15;
    const int lg  = l >> 4;

    f32x4_t acc[4][4];
#pragma unroll
    for (int i = 0; i < 4; ++i)
#pragma unroll
        for (int j = 0; j < 4; ++j)
            acc[i][j] = (f32x4_t){0.f, 0.f, 0.f, 0.f};

    bf16x8_t bfp[2][4], afp[2][4];
#pragma unroll
    for (int nf = 0; nf < 4; ++nf)
        bfp[0][nf] = *(const bf16x8_t*)(wt + (((size_t)(0 * 4 + nf)) * 64 + l) * 8);
    {
        int colr = l15;
        int chunk = lg ^ (colr & 7);
#pragma unroll
        for (int mf = 0; mf < 4; ++mf)
            afp[0][mf] = *(const bf16x8_t*)&tile[((wv * 4 + mf) * 18 + colr) * 64 + chunk * 8];
    }
#pragma unroll
    for (int kc = 0; kc < 18; ++kc) {
        const int cur = kc & 1, nxt = cur ^ 1;
        if (kc + 1 < 18) {
            int kn = kc + 1;
#pragma unroll
            for (int nf = 0; nf < 4; ++nf)
                bfp[nxt][nf] = *(const bf16x8_t*)(wt + (((size_t)(kn * 4 + nf)) * 64 + l) * 8);
            int tap = kn >> 1;
            int dy = tap / 3, dx = tap % 3;
            int colr = l15 + dx;
            int chunk = (((kn & 1) << 2) + lg) ^ (colr & 7);
#pragma unroll
            for (int mf = 0; mf < 4; ++mf)
                afp[nxt][mf] = *(const bf16x8_t*)&tile[((wv * 4 + mf + dy) * 18 + colr) * 64 + chunk * 8];
        }
#pragma unroll
        for (int mf = 0; mf < 4; ++mf)
#pragma unroll
            for (int nf = 0; nf < 4; ++nf)
                acc[mf][nf] = __builtin_amdgcn_mfma_f32_16x16x32_bf16(
                    afp[cur][mf], bfp[cur][nf], acc[mf][nf], 0, 0, 0);
    }

    __syncthreads();
#pragma unroll
    for (int mf = 0; mf < 4; ++mf) {
        int py = wv * 4 + mf;
#pragma unroll
        for (int nf = 0; nf < 4; ++nf) {
            int oc = nf * 16 + l15;
#pragma unroll
            for (int k = 0; k < 4; ++k)
                tile[((py * 16) + lg * 4 + k) * 64 + oc] = f_to_bf16(acc[mf][nf][k]);
        }
    }
    __syncthreads();
    short* outb = outh + (size_t)b * HW * 64;
#pragma unroll
    for (int j = 0; j < 8; ++j) {
        int item = j * 256 + tid;
        int c8  = item & 7;
        int pix = item >> 3;
        int py  = pix >> 4, px = pix & 15;
        *(bf16x8_t*)&outb[((size_t)(y0 + py) * W + x0 + px) * 64 + c8 * 8] =
            *(bf16x8_t*)&tile[pix * 64 + c8 * 8];
    }

#pragma unroll
    for (int nf = 0; nf < 4; ++nf) {
        float s = 0.f, s2 = 0.f;
#pragma unroll
        for (int mf = 0; mf < 4; ++mf)
#pragma unroll
            for (int k = 0; k < 4; ++k) {
                float v = acc[mf][nf][k];
                s += v; s2 += v * v;
            }
        s  += __shfl_xor(s, 16, 64);  s  += __shfl_xor(s, 32, 64);
        s2 += __shfl_xor(s2, 16, 64); s2 += __shfl_xor(s2, 32, 64);
        if (lg == 0) {
            int oc = nf * 16 + l15;
            atomicAdd(&sstat[oc], s);
            atomicAdd(&sstat[64 + oc], s2);
        }
    }
    __syncthreads();
    float* st = stats + (size_t)(blockIdx.x & 7) * 128;
    if (tid < 128) atomicAdd(&st[tid], sstat[tid]);
}

// ------------------------------------------------- BN apply dual
__global__ void bn_apply_dual_kernel(const short* __restrict__ in,
                                     const float* __restrict__ stats,
                                     float* __restrict__ out,
                                     short* __restrict__ outh,
                                     int HW, float invN)
{
    __shared__ float ftile[64][65];
    __shared__ float sm[64], sr[64];
    int nchunks = HW >> 6;
    int b  = blockIdx.x / nchunks;
    int p0 = (blockIdx.x % nchunks) << 6;
    int tid = threadIdx.x;
    if (tid < 64) {
        float s = 0.f, s2 = 0.f;
#pragma unroll
        for (int k = 0; k < 8; ++k) {
            s  += stats[k * 128 + tid];
            s2 += stats[k * 128 + 64 + tid];
        }
        float mean = s * invN;
        float var  = s2 * invN - mean * mean;
        sm[tid] = mean;
        sr[tid] = rsqrtf(var + 1e-5f);
    }
    __syncthreads();
#pragma unroll
    for (int it = 0; it < 2; ++it) {
        int item = it * 256 + tid;
        int p = item >> 3, c0 = (item & 7) * 8;
        size_t gi = ((size_t)(b * HW + p0 + p)) * 64 + c0;
        bf16x8_t v = *(const bf16x8_t*)&in[gi];
        bf16x8_t o;
#pragma unroll
        for (int j = 0; j < 8; ++j) {
            float f = (bf16_to_f((unsigned short)v[j]) - sm[c0 + j]) * sr[c0 + j];
            f = f > 0.f ? f : 0.f;
            ftile[p][c0 + j] = f;
            o[j] = f_to_bf16(f);
        }
        *(bf16x8_t*)&outh[gi] = o;
    }
    __syncthreads();
#pragma unroll
    for (int rep = 0; rep < 16; ++rep) {
        int item = rep * 256 + tid;
        int c = item >> 6, p = item & 63;
        out[((size_t)b * 64 + c) * HW + p0 + p] = ftile[p][c];
    }
}

// ------------------------------------------------- offset2/3: MFMA conv, N=18
__global__ __launch_bounds__(256, 1) void offconv_mfma_kernel(
    const short* __restrict__ xh,
    const short* __restrict__ wt,
    const float* __restrict__ bias,
    float* __restrict__ out,
    int H, int W, int Ho, int Wo)
{
    const int HW = Ho * Wo;
    const int tid = threadIdx.x;
    const int wv = tid >> 6, l = tid & 63;
    const int l15 = l & 15, lg = l >> 4;
    const int pix0 = blockIdx.x * 64 + wv * 16;
    const int b = pix0 / HW;
    const int r0 = pix0 - b * HW;

    int rp = r0 + l15;
    int ho = rp / Wo, wo = rp % Wo;
    const short* xb = xh + (size_t)b * H * W * 64;

    f32x4_t acc[2];
    acc[0] = (f32x4_t){0.f, 0.f, 0.f, 0.f};
    acc[1] = (f32x4_t){0.f, 0.f, 0.f, 0.f};

#pragma unroll 2
    for (int kc = 0; kc < 18; ++kc) {
        int tap = kc >> 1;
        int iy = ho * 2 - 1 + tap / 3;
        int ix = wo * 2 - 1 + tap % 3;
        bf16x8_t af = {};
        if (iy >= 0 && iy < H && ix >= 0 && ix < W)
            af = *(const bf16x8_t*)&xb[((size_t)iy * W + ix) * 64
                                       + (kc & 1) * 32 + lg * 8];
#pragma unroll
        for (int nf = 0; nf < 2; ++nf) {
            bf16x8_t bf = *(const bf16x8_t*)(wt + (((size_t)(kc * 2 + nf)) * 64 + l) * 8);
            acc[nf] = __builtin_amdgcn_mfma_f32_16x16x32_bf16(af, bf, acc[nf], 0, 0, 0);
        }
    }

#pragma unroll
    for (int nf = 0; nf < 2; ++nf) {
        int oc = nf * 16 + l15;
        if (oc < 18) {
            float bv = bias[oc];
            f32x4_t v = acc[nf];
            v[0] += bv; v[1] += bv; v[2] += bv; v[3] += bv;
            *(f32x4_t*)&out[((size_t)(b * 18 + oc)) * HW + r0 + lg * 4] = v;
        }
    }
}

// ------------------------------------------------- deform1: fused offset1 +
// deform (C=3, MFMA MAC) + skip; x4 is bf16 NHWC4
__global__ __launch_bounds__(256, 1) void deform1_kernel(
    const unsigned short* __restrict__ x4,
    const float* __restrict__ wof,
    const float* __restrict__ bof,
    const short* __restrict__ wtd1,
    const float* __restrict__ bias,
    const float* __restrict__ pool,
    const float* __restrict__ wsk,
    const float* __restrict__ bsk,
    short* __restrict__ outh)
{
    const int H = 640, W = 640, Ho = 160, Wo = 160, HW = 25600;
    constexpr int P = 32;
    __shared__ float xtap[P * 9][4];
    __shared__ float swof[486];
    __shared__ float sbof[18];
    __shared__ float spool[3][P];
    __shared__ float off1[P][18];
    __shared__ alignas(16) short sampb[P][40];
    __shared__ int   sidx[P * 9][4];
    __shared__ float swt[P * 9][4];
    const int tid = threadIdx.x;
    const int pix0 = blockIdx.x * P;
    const int b = pix0 / HW;
    const int r0 = pix0 - b * HW;
    const unsigned short* xb = x4 + (size_t)b * H * W * 4;

    for (int item = tid; item < P * 9; item += TPB) {
        int p = item / 9, tap = item % 9;
        int r = r0 + p, ho = r / Wo, wo = r % Wo;
        int iy = ho * 4 - 1 + tap / 3;
        int ix = wo * 4 - 1 + tap % 3;
        f32x4_t s = (f32x4_t){0.f, 0.f, 0.f, 0.f};
        if (iy >= 0 && iy < H && ix >= 0 && ix < W) {
            u16x4_t u = *(const u16x4_t*)&xb[((size_t)iy * W + ix) * 4];
            s[0] = bf16_to_f(u[0]);
            s[1] = bf16_to_f(u[1]);
            s[2] = bf16_to_f(u[2]);
        }
        *(f32x4_t*)xtap[item] = s;
    }
    for (int i = tid; i < P * 40; i += TPB) ((short*)sampb)[i] = 0;
    for (int i = tid; i < 96; i += TPB) {
        int c = i >> 5, p = i & 31;
        spool[c][p] = pool[((size_t)(b * 3 + c)) * HW + r0 + p];
    }
    for (int item = tid; item < 486; item += TPB) swof[item] = wof[item];
    if (tid < 18) sbof[tid] = bof[tid];
    __syncthreads();

    for (int item = tid; item < P * 18; item += TPB) {
        int p = item / 18, o = item % 18;
        float acc = sbof[o];
#pragma unroll
        for (int tap = 0; tap < 9; ++tap) {
            const float* xt = xtap[p * 9 + tap];
#pragma unroll
            for (int c = 0; c < 3; ++c)
                acc += xt[c] * swof[(o * 3 + c) * 9 + tap];
        }
        off1[p][o] = acc;
    }
    __syncthreads();

    for (int item = tid; item < P * 9; item += TPB) {
        int p = item / 9, tap = item % 9;
        int r = r0 + p, ho = r / Wo, wo = r % Wo;
        float dy = off1[p][2 * tap];
        float dx = off1[p][2 * tap + 1];
        float ys = (float)(ho * 4 - 1 + tap / 3) + dy;
        float xs = (float)(wo * 4 - 1 + tap % 3) + dx;
        float y0f = floorf(ys), x0f = floorf(xs);
        float fy = ys - y0f, fx = xs - x0f;
        int y0 = (int)y0f, x0 = (int)x0f;
        float wts[4] = {(1.f - fy) * (1.f - fx), (1.f - fy) * fx,
                        fy * (1.f - fx),          fy * fx};
#pragma unroll
        for (int j = 0; j < 4; ++j) {
            int iy = y0 + (j >> 1), ix = x0 + (j & 1);
            bool v = (iy >= 0) && (iy < H) && (ix >= 0) && (ix < W);
            sidx[item][j] = v ? (iy * W + ix) : 0;
            swt[item][j]  = v ? wts[j] : 0.f;
        }
    }
    __syncthreads();

    for (int item = tid; item < P * 9; item += TPB) {
        int p = item / 9, tap = item % 9;
        i32x4_t id4 = *(const i32x4_t*)sidx[item];
        f32x4_t w4  = *(const f32x4_t*)swt[item];
        u16x4_t a0 = *(const u16x4_t*)&xb[(size_t)(unsigned)id4[0] * 4];
        u16x4_t a1 = *(const u16x4_t*)&xb[(size_t)(unsigned)id4[1] * 4];
        u16x4_t a2 = *(const u16x4_t*)&xb[(size_t)(unsigned)id4[2] * 4];
        u16x4_t a3 = *(const u16x4_t*)&xb[(size_t)(unsigned)id4[3] * 4];
        sampb[p][0 * 9 + tap] = f_to_bf16(
            w4[0]*bf16_to_f(a0[0]) + w4[1]*bf16_to_f(a1[0])
          + w4[2]*bf16_to_f(a2[0]) + w4[3]*bf16_to_f(a3[0]));
        sampb[p][1 * 9 + tap] = f_to_bf16(
            w4[0]*bf16_to_f(a0[1]) + w4[1]*bf16_to_f(a1[1])
          + w4[2]*bf16_to_f(a2[1]) + w4[3]*bf16_to_f(a3[1]));
        sampb[p][2 * 9 + tap] = f_to_bf16(
            w4[0]*bf16_to_f(a0[2]) + w4[1]*bf16_to_f(a1[2])
          + w4[2]*bf16_to_f(a2[2]) + w4[3]*bf16_to_f(a3[2]));
    }
    __syncthreads();

    const int wv = tid >> 6;
    const int l  = tid & 63;
    const int l15 = l & 15, lg = l >> 4;
    bf16x8_t bf  = *(const bf16x8_t*)(wtd1 + (((size_t)wv * 64 + l)) * 8);
    bf16x8_t af0 = *(const bf16x8_t*)&sampb[l15][lg * 8];
    bf16x8_t af1 = *(const bf16x8_t*)&sampb[l15 + 16][lg * 8];
    f32x4_t z = (f32x4_t){0.f, 0.f, 0.f, 0.f};
    f32x4_t acc0 = __builtin_amdgcn_mfma_f32_16x16x32_bf16(af0, bf, z, 0, 0, 0);
    f32x4_t acc1 = __builtin_amdgcn_mfma_f32_16x16x32_bf16(af1, bf, z, 0, 0, 0);

    int oc = wv * 16 + l15;
    float bb = bias[oc] + bsk[oc];
    float w0 = wsk[oc * 3 + 0], w1 = wsk[oc * 3 + 1], w2 = wsk[oc * 3 + 2];
    short* otile = (short*)xtap;
    __syncthreads();
#pragma unroll
    for (int mf = 0; mf < 2; ++mf) {
        f32x4_t a = mf ? acc1 : acc0;
#pragma unroll
        for (int k = 0; k < 4; ++k) {
            int px = mf * 16 + lg * 4 + k;
            float sv = w0 * spool[0][px] + w1 * spool[1][px] + w2 * spool[2][px];
            otile[px * 64 + oc] = f_to_bf16(a[k] + bb + sv);
        }
    }
    __syncthreads();
    {
        int c8 = tid & 7, px = tid >> 3;
        *(bf16x8_t*)&outh[((size_t)(b * HW + r0 + px)) * 64 + c8 * 8] =
            *(bf16x8_t*)&otile[px * 64 + c8 * 8];
    }
}

// ------------------------------------------------- deform MFMA: C=64 -> O
template <int O, int DUAL>
__global__ __launch_bounds__(256, 1) void deform_mfma_kernel(
    const short* __restrict__ xh,
    const float* __restrict__ off,
    const short* __restrict__ wt,
    const float* __restrict__ bias,
    float* __restrict__ out,
    short* __restrict__ outh,
    int H, int W, int Ho, int Wo, int stride)
{
    constexpr int NF = O / 64;
    constexpr int NFRAG = O / 16;
    constexpr int P  = 32;
    __shared__ alignas(16) short samp[P * 576];
    __shared__ int   sidx[P * 9][4];
    __shared__ float swt[P * 9][4];

    const int tid = threadIdx.x;
    const int HW = Ho * Wo;
    const int pix0 = blockIdx.x * P;
    const int b = pix0 / HW;
    const int r0 = pix0 - b * HW;

    for (int item = tid; item < P * 9; item += TPB) {
        int p = item / 9, tap = item % 9;
        int r = r0 + p, ho = r / Wo, wo = r % Wo;
        float dy = off[((size_t)(b * 18 + 2 * tap) * Ho + ho) * Wo + wo];
        float dx = off[((size_t)(b * 18 + 2 * tap + 1) * Ho + ho) * Wo + wo];
        float ys = (float)(ho * stride - 1 + tap / 3) + dy;
        float xs = (float)(wo * stride - 1 + tap % 3) + dx;
        float y0f = floorf(ys), x0f = floorf(xs);
        float fy = ys - y0f, fx = xs - x0f;
        int y0 = (int)y0f, x0 = (int)x0f;
        float wts[4] = {(1.f - fy) * (1.f - fx), (1.f - fy) * fx,
                        fy * (1.f - fx),          fy * fx};
#pragma unroll
        for (int j = 0; j < 4; ++j) {
            int iy = y0 + (j >> 1), ix = x0 + (j & 1);
            bool v = (iy >= 0) && (iy < H) && (ix >= 0) && (ix < W);
            sidx[item][j] = v ? (iy * W + ix) : 0;
            swt[item][j]  = v ? wts[j] : 0.f;
        }
    }
    __syncthreads();

    {
        const int p  = tid >> 3;
        const int ic = (tid & 7) * 8;
        const int swc = (ic >> 3) ^ (p & 7);
        const short* xb = xh + (size_t)b * H * W * 64;
#pragma unroll 3
        for (int tap = 0; tap < 9; ++tap) {
            int e = p * 9 + tap;
            i32x4_t id4 = *(const i32x4_t*)sidx[e];
            f32x4_t w4  = *(const f32x4_t*)swt[e];
            u16x8_t u0 = *(const u16x8_t*)&xb[(size_t)(unsigned)id4[0] * 64 + ic];
            u16x8_t u1 = *(const u16x8_t*)&xb[(size_t)(unsigned)id4[1] * 64 + ic];
            u16x8_t u2 = *(const u16x8_t*)&xb[(size_t)(unsigned)id4[2] * 64 + ic];
            u16x8_t u3 = *(const u16x8_t*)&xb[(size_t)(unsigned)id4[3] * 64 + ic];
            bf16x8_t o;
#pragma unroll
            for (int j = 0; j < 8; ++j) {
                float v = w4[0]*bf16_to_f(u0[j]) + w4[1]*bf16_to_f(u1[j])
                        + w4[2]*bf16_to_f(u2[j]) + w4[3]*bf16_to_f(u3[j]);
                o[j] = f_to_bf16(v);
            }
            *(bf16x8_t*)&samp[p * 576 + (tap * 8 + swc) * 8] = o;
        }
    }
    __syncthreads();

    const int wv = tid >> 6;
    const int l  = tid & 63;
    const int l15 = l & 15, lg = l >> 4;
    f32x4_t acc[2][NF];
#pragma unroll
    for (int mf = 0; mf < 2; ++mf)
#pragma unroll
        for (int nf = 0; nf < NF; ++nf)
            acc[mf][nf] = (f32x4_t){0.f, 0.f, 0.f, 0.f};

#pragma unroll 2
    for (int kc = 0; kc < 18; ++kc) {
        int tap = kc >> 1;
        int low = (((kc & 1) << 2) | lg) ^ (l15 & 7);
        bf16x8_t af0 = *(const bf16x8_t*)&samp[l15 * 576 + (tap * 8 + low) * 8];
        bf16x8_t af1 = *(const bf16x8_t*)&samp[(l15 + 16) * 576 + (tap * 8 + low) * 8];
#pragma unroll
        for (int nf = 0; nf < NF; ++nf) {
            int ocf = wv * NF + nf;
            bf16x8_t bf = *(const bf16x8_t*)(wt + (((size_t)(kc * NFRAG + ocf)) * 64 + l) * 8);
            acc[0][nf] = __builtin_amdgcn_mfma_f32_16x16x32_bf16(af0, bf, acc[0][nf], 0, 0, 0);
            acc[1][nf] = __builtin_amdgcn_mfma_f32_16x16x32_bf16(af1, bf, acc[1][nf], 0, 0, 0);
        }
    }

#pragma unroll
    for (int mf = 0; mf < 2; ++mf)
#pragma unroll
        for (int nf = 0; nf < NF; ++nf) {
            int oc = (wv * NF + nf) * 16 + l15;
            float bv = bias[oc];
            f32x4_t v = acc[mf][nf];
            v[0] += bv; v[1] += bv; v[2] += bv; v[3] += bv;
            acc[mf][nf] = v;
            *(f32x4_t*)&out[((size_t)(b * O + oc)) * HW + r0 + mf * 16 + lg * 4] = v;
        }

    if (DUAL) {
        __syncthreads();
        short* otile = samp;
#pragma unroll
        for (int mf = 0; mf < 2; ++mf) {
            int oc = wv * 16 + l15;
#pragma unroll
            for (int k = 0; k < 4; ++k) {
                int px = mf * 16 + lg * 4 + k;
                otile[px * 64 + oc] = f_to_bf16(acc[mf][0][k]);
            }
        }
        __syncthreads();
        int c8 = tid & 7, px = tid >> 3;
        *(bf16x8_t*)&outh[((size_t)(b * HW + r0 + px)) * 64 + c8 * 8] =
            *(bf16x8_t*)&otile[px * 64 + c8 * 8];
    }
}

// ---------------------------------------------------------------- launch
extern "C" void kernel_launch(void* const* d_in, const int* in_sizes, int n_in,
                              void* d_out, int out_size, void* d_ws, size_t ws_size,
                              hipStream_t stream)
{
    const float* x      = (const float*)d_in[0];
    const float* w_off1 = (const float*)d_in[1];
    const float* b_off1 = (const float*)d_in[2];
    const float* w_d1   = (const float*)d_in[3];
    const float* b_d1   = (const float*)d_in[4];
    const float* w_skip = (const float*)d_in[5];
    const float* b_skip = (const float*)d_in[6];
    const float* w_bl1  = (const float*)d_in[7];
    const float* w_bl2  = (const float*)d_in[8];
    const float* w_off2 = (const float*)d_in[9];
    const float* b_off2 = (const float*)d_in[10];
    const float* w_d2   = (const float*)d_in[11];
    const float* b_d2   = (const float*)d_in[12];
    const float* w_off3 = (const float*)d_in[13];
    const float* b_off3 = (const float*)d_in[14];
    const float* w_d3   = (const float*)d_in[15];
    const float* b_d3   = (const float*)d_in[16];

    const int B = 8;
    float* A     = (float*)d_ws;
    float* bufB  = A + 3686400;
    float* bufC  = bufB + 13107200;

    short* hB   = (short*)bufB;
    short* hC   = (short*)bufC;
    float* pool = bufB + 8000000;

    short* wt1    = (short*)(A + 1000000);
    short* wt2    = wt1 + 18 * 4 * 512;
    short* wtd2   = (short*)(A + 1500000);
    short* wtd3   = (short*)(A + 1550000);
    short* wtoff2 = (short*)(A + 1700000);
    short* wtoff3 = (short*)(A + 1712000);
    short* wtd1   = (short*)(A + 1750000);
    float* stats1 = A + 1800000;
    float* stats2 = stats1 + 1024;
    float* zpage  = stats1 + 2048;

    float* out0 = (float*)d_out;
    float* out1 = out0 + 13107200;
    float* out2 = out1 + 3276800;

    const float invN = 1.0f / (B * 25600);

    prep_kernel<<<(8 * 25600 + TPB - 1) / TPB, TPB, 0, stream>>>(
        x, (unsigned short*)bufC, pool);

    repack_all_kernel<<<(299520 + TPB - 1) / TPB, TPB, 0, stream>>>(
        w_bl1, wt1, w_bl2, wt2, w_d2, wtd2, w_d3, wtd3,
        w_off2, wtoff2, w_off3, wtoff3, w_d1, wtd1, stats1);

    deform1_kernel<<<8 * 25600 / 32, TPB, 0, stream>>>(
        (const unsigned short*)bufC, w_off1, b_off1, wtd1, b_d1,
        pool, w_skip, b_skip, hB);

    conv3x3_mfma_kernel<0><<<800, TPB, 0, stream>>>(
        hB, wt1, hC, stats1, nullptr, invN, zpage);

    conv3x3_mfma_kernel<1><<<800, TPB, 0, stream>>>(
        hC, wt2, hB, stats2, stats1, invN, zpage);

    bn_apply_dual_kernel<<<8 * 400, TPB, 0, stream>>>(
        hB, stats2, out0, hC, 25600, invN);

    offconv_mfma_kernel<<<8 * 6400 / 64, TPB, 0, stream>>>(
        hC, wtoff2, b_off2, A, 160, 160, 80, 80);

    deform_mfma_kernel<64, 1><<<8 * 6400 / 32, TPB, 0, stream>>>(
        hC, A, wtd2, b_d2, out1, hB, 160, 160, 80, 80, 2);

    offconv_mfma_kernel<<<8 * 1600 / 64, TPB, 0, stream>>>(
        hB, wtoff3, b_off3, A, 80, 80, 40, 40);

    deform_mfma_kernel<256, 0><<<8 * 1600 / 32, TPB, 0, stream>>>(
        hB, A, wtd3, b_d3, out2, nullptr, 80, 80, 40, 40, 2);
}

// Round 22
// 205.686 us; speedup vs baseline: 1.1051x; 1.0001x over previous
//
#include <hip/hip_runtime.h>
#include <hip/hip_bf16.h>
#include <math.h>

#define TPB 256

typedef __attribute__((ext_vector_type(8))) short bf16x8_t;
typedef __attribute__((ext_vector_type(4))) float f32x4_t;
typedef __attribute__((ext_vector_type(4))) int i32x4_t;
typedef __attribute__((ext_vector_type(4))) unsigned short u16x4_t;
typedef __attribute__((ext_vector_type(8))) unsigned short u16x8_t;

#if defined(__has_builtin)
#if __has_builtin(__builtin_amdgcn_global_load_lds)
#define HAS_GLOAD_LDS 1
#endif
#endif

static __device__ __forceinline__ float bf16_to_f(unsigned short s) {
    union { unsigned u; float f; } cv;
    cv.u = ((unsigned)s) << 16;
    return cv.f;
}
static __device__ __forceinline__ short f_to_bf16(float v) {
    __hip_bfloat16 h = __float2bfloat16(v);
    return *(short*)&h;
}

// ------------------------------------------------- prep: x NCHW -> x4 NHWC4 bf16 + pool
__global__ void prep_kernel(const float* __restrict__ in,
                            unsigned short* __restrict__ x4,
                            float* __restrict__ pool)
{
    const int HWo = 25600, H = 640, W = 640;
    int idx = blockIdx.x * TPB + threadIdx.x;
    if (idx >= 8 * HWo) return;
    int b = idx / HWo, r = idx % HWo;
    int ho = r / 160, wo = r % 160;
    float s0 = 0.f, s1 = 0.f, s2 = 0.f;
    unsigned short* x4b = x4 + (size_t)b * H * W * 4;
#pragma unroll
    for (int dy = 0; dy < 4; ++dy) {
        int row = ho * 4 + dy;
        size_t base = ((size_t)row * W + wo * 4);
        f32x4_t a0 = *(const f32x4_t*)&in[((size_t)(b * 3 + 0) * H * W) + base];
        f32x4_t a1 = *(const f32x4_t*)&in[((size_t)(b * 3 + 1) * H * W) + base];
        f32x4_t a2 = *(const f32x4_t*)&in[((size_t)(b * 3 + 2) * H * W) + base];
        s0 += a0[0] + a0[1] + a0[2] + a0[3];
        s1 += a1[0] + a1[1] + a1[2] + a1[3];
        s2 += a2[0] + a2[1] + a2[2] + a2[3];
#pragma unroll
        for (int dx = 0; dx < 4; ++dx) {
            u16x4_t v;
            v[0] = (unsigned short)f_to_bf16(a0[dx]);
            v[1] = (unsigned short)f_to_bf16(a1[dx]);
            v[2] = (unsigned short)f_to_bf16(a2[dx]);
            v[3] = 0;
            *(u16x4_t*)&x4b[(base + dx) * 4] = v;
        }
    }
    pool[((size_t)(b * 3 + 0)) * HWo + r] = s0 * (1.0f / 16.0f);
    pool[((size_t)(b * 3 + 1)) * HWo + r] = s1 * (1.0f / 16.0f);
    pool[((size_t)(b * 3 + 2)) * HWo + r] = s2 * (1.0f / 16.0f);
}

// ------------------------------------------------- single repack-everything kernel
static __device__ __forceinline__ void repack_one(
    const float* __restrict__ w, short* __restrict__ wtf,
    int idx, int Oreal, int NFRAG)
{
    int j    = idx & 7;
    int lane = (idx >> 3) & 63;
    int t    = idx >> 9;
    int ocf  = t % NFRAG;
    int kc   = t / NFRAG;
    int oc   = ocf * 16 + (lane & 15);
    int tap  = kc >> 1;
    int ic   = (kc & 1) * 32 + (lane >> 4) * 8 + j;
    float v = 0.f;
    if (oc < Oreal)
        v = w[((size_t)(oc * 64 + ic)) * 9 + tap];
    wtf[idx] = f_to_bf16(v);
}

__global__ void repack_all_kernel(
    const float* __restrict__ w_bl1, short* __restrict__ wt1,
    const float* __restrict__ w_bl2, short* __restrict__ wt2,
    const float* __restrict__ w_d2,  short* __restrict__ wtd2,
    const float* __restrict__ w_d3,  short* __restrict__ wtd3,
    const float* __restrict__ w_off2, short* __restrict__ wtoff2,
    const float* __restrict__ w_off3, short* __restrict__ wtoff3,
    const float* __restrict__ w_d1,  short* __restrict__ wtd1,
    float* __restrict__ stats)
{
    int idx = blockIdx.x * TPB + threadIdx.x;
    if (idx < 36864) { repack_one(w_bl1, wt1, idx, 64, 4); return; }
    idx -= 36864;
    if (idx < 36864) { repack_one(w_bl2, wt2, idx, 64, 4); return; }
    idx -= 36864;
    if (idx < 36864) { repack_one(w_d2, wtd2, idx, 64, 4); return; }
    idx -= 36864;
    if (idx < 147456) { repack_one(w_d3, wtd3, idx, 256, 16); return; }
    idx -= 147456;
    if (idx < 18432) { repack_one(w_off2, wtoff2, idx, 18, 2); return; }
    idx -= 18432;
    if (idx < 18432) { repack_one(w_off3, wtoff3, idx, 18, 2); return; }
    idx -= 18432;
    if (idx < 2048) {
        int j = idx & 7, lane = (idx >> 3) & 63, ocf = idx >> 9;
        int oc = ocf * 16 + (lane & 15);
        int k  = (lane >> 4) * 8 + j;
        float v = 0.f;
        if (k < 27) v = w_d1[(size_t)oc * 27 + k];
        wtd1[idx] = f_to_bf16(v);
        return;
    }
    idx -= 2048;
    if (idx < 2560) stats[idx] = 0.f;
}

// ------------------------------------------------- MFMA conv 3x3 (64->64, s1)
template <int NORM>
__global__ __launch_bounds__(256, 2) void conv3x3_mfma_kernel(
    const short* __restrict__ xh,
    const short* __restrict__ wt,
    short* __restrict__ outh,
    float* __restrict__ stats,
    const float* __restrict__ stats_in,
    float invN,
    const float* __restrict__ zp)
{
    __shared__ short tile[2816 * 8];
    __shared__ float sstat[128];
    __shared__ float sm[64], sr[64];
    const int H = 160, W = 160, HW = 25600;
    int blk = blockIdx.x;
    int b  = blk / 100;
    int r  = blk % 100;
    int y0 = (r / 10) * 16;
    int x0 = (r % 10) * 16;
    const int tid = threadIdx.x;
    const short* inb = xh + (size_t)b * HW * 64;

    if (tid < 128) sstat[tid] = 0.f;
    if (NORM) {
        if (tid < 64) {
            float s = 0.f, s2 = 0.f;
#pragma unroll
            for (int k = 0; k < 8; ++k) {
                s  += stats_in[k * 128 + tid];
                s2 += stats_in[k * 128 + 64 + tid];
            }
            float mean = s * invN;
            float var  = s2 * invN - mean * mean;
            sm[tid] = mean;
            sr[tid] = rsqrtf(var + 1e-5f);
        }
        __syncthreads();
    }

    if (NORM == 0) {
#ifdef HAS_GLOAD_LDS
#pragma unroll
        for (int it = 0; it < 11; ++it) {
            int item = it * 256 + tid;
            int c8  = item & 7;
            int pix = item >> 3;
            int row = pix / 18;
            int col = pix - row * 18;
            int y = y0 + row - 1;
            int x = x0 + col - 1;
            bool ok = (pix < 324) & (y >= 0) & (y < H) & (x >= 0) & (x < W);
            int cs = c8 ^ (col & 7);
            const short* src = ok
                ? &inb[((size_t)y * W + x) * 64 + (cs << 3)]
                : (const short*)zp;
            __builtin_amdgcn_global_load_lds(
                (const __attribute__((address_space(1))) unsigned int*)src,
                (__attribute__((address_space(3))) unsigned int*)
                    &tile[(it * 256 + (tid & 192)) * 8],
                16, 0, 0);
        }
#else
#pragma unroll
        for (int it = 0; it < 11; ++it) {
            int item = it * 256 + tid;
            int c8  = item & 7;
            int pix = item >> 3;
            int row = pix / 18;
            int col = pix - row * 18;
            int y = y0 + row - 1;
            int x = x0 + col - 1;
            bool ok = (pix < 324) & (y >= 0) & (y < H) & (x >= 0) & (x < W);
            int cs = c8 ^ (col & 7);
            const short* src = ok
                ? &inb[((size_t)y * W + x) * 64 + (cs << 3)]
                : (const short*)zp;
            *(bf16x8_t*)&tile[item * 8] = *(const bf16x8_t*)src;
        }
#endif
    } else {
#pragma unroll
        for (int it = 0; it < 11; ++it) {
            int item = it * 256 + tid;
            int c8  = item & 7;
            int pix = item >> 3;
            int row = pix / 18;
            int col = pix - row * 18;
            int y = y0 + row - 1;
            int x = x0 + col - 1;
            bool ok = (pix < 324) & (y >= 0) & (y < H) & (x >= 0) & (x < W);
            int cs = c8 ^ (col & 7);
            const short* src = ok
                ? &inb[((size_t)y * W + x) * 64 + (cs << 3)]
                : (const short*)zp;
            bf16x8_t v = *(const bf16x8_t*)src;
            int cs8 = cs << 3;
            bf16x8_t o;
#pragma unroll
            for (int j = 0; j < 8; ++j) {
                float f = (bf16_to_f((unsigned short)v[j]) - sm[cs8 + j]) * sr[cs8 + j];
                f = f > 0.f ? f : 0.f;
                o[j] = ok ? f_to_bf16(f) : (short)0;
            }
            *(bf16x8_t*)&tile[item * 8] = o;
        }
    }
    __syncthreads();

    const int wv  = tid >> 6;
    const int l   = tid & 63;
    const int l15 = l & 15;
    const int lg  = l >> 4;

    f32x4_t acc[4][4];
#pragma unroll
    for (int i = 0; i < 4; ++i)
#pragma unroll
        for (int j = 0; j < 4; ++j)
            acc[i][j] = (f32x4_t){0.f, 0.f, 0.f, 0.f};

    bf16x8_t bfp[2][4], afp[2][4];
#pragma unroll
    for (int nf = 0; nf < 4; ++nf)
        bfp[0][nf] = *(const bf16x8_t*)(wt + (((size_t)(0 * 4 + nf)) * 64 + l) * 8);
    {
        int colr = l15;
        int chunk = lg ^ (colr & 7);
#pragma unroll
        for (int mf = 0; mf < 4; ++mf)
            afp[0][mf] = *(const bf16x8_t*)&tile[((wv * 4 + mf) * 18 + colr) * 64 + chunk * 8];
    }
#pragma unroll
    for (int kc = 0; kc < 18; ++kc) {
        const int cur = kc & 1, nxt = cur ^ 1;
        if (kc + 1 < 18) {
            int kn = kc + 1;
#pragma unroll
            for (int nf = 0; nf < 4; ++nf)
                bfp[nxt][nf] = *(const bf16x8_t*)(wt + (((size_t)(kn * 4 + nf)) * 64 + l) * 8);
            int tap = kn >> 1;
            int dy = tap / 3, dx = tap % 3;
            int colr = l15 + dx;
            int chunk = (((kn & 1) << 2) + lg) ^ (colr & 7);
#pragma unroll
            for (int mf = 0; mf < 4; ++mf)
                afp[nxt][mf] = *(const bf16x8_t*)&tile[((wv * 4 + mf + dy) * 18 + colr) * 64 + chunk * 8];
        }
#pragma unroll
        for (int mf = 0; mf < 4; ++mf)
#pragma unroll
            for (int nf = 0; nf < 4; ++nf)
                acc[mf][nf] = __builtin_amdgcn_mfma_f32_16x16x32_bf16(
                    afp[cur][mf], bfp[cur][nf], acc[mf][nf], 0, 0, 0);
    }

    __syncthreads();
#pragma unroll
    for (int mf = 0; mf < 4; ++mf) {
        int py = wv * 4 + mf;
#pragma unroll
        for (int nf = 0; nf < 4; ++nf) {
            int oc = nf * 16 + l15;
#pragma unroll
            for (int k = 0; k < 4; ++k)
                tile[((py * 16) + lg * 4 + k) * 64 + oc] = f_to_bf16(acc[mf][nf][k]);
        }
    }
    __syncthreads();
    short* outb = outh + (size_t)b * HW * 64;
#pragma unroll
    for (int j = 0; j < 8; ++j) {
        int item = j * 256 + tid;
        int c8  = item & 7;
        int pix = item >> 3;
        int py  = pix >> 4, px = pix & 15;
        *(bf16x8_t*)&outb[((size_t)(y0 + py) * W + x0 + px) * 64 + c8 * 8] =
            *(bf16x8_t*)&tile[pix * 64 + c8 * 8];
    }

#pragma unroll
    for (int nf = 0; nf < 4; ++nf) {
        float s = 0.f, s2 = 0.f;
#pragma unroll
        for (int mf = 0; mf < 4; ++mf)
#pragma unroll
            for (int k = 0; k < 4; ++k) {
                float v = acc[mf][nf][k];
                s += v; s2 += v * v;
            }
        s  += __shfl_xor(s, 16, 64);  s  += __shfl_xor(s, 32, 64);
        s2 += __shfl_xor(s2, 16, 64); s2 += __shfl_xor(s2, 32, 64);
        if (lg == 0) {
            int oc = nf * 16 + l15;
            atomicAdd(&sstat[oc], s);
            atomicAdd(&sstat[64 + oc], s2);
        }
    }
    __syncthreads();
    float* st = stats + (size_t)(blockIdx.x & 7) * 128;
    if (tid < 128) atomicAdd(&st[tid], sstat[tid]);
}

// ------------------------------------------------- BN apply dual
__global__ void bn_apply_dual_kernel(const short* __restrict__ in,
                                     const float* __restrict__ stats,
                                     float* __restrict__ out,
                                     short* __restrict__ outh,
                                     int HW, float invN)
{
    __shared__ float ftile[64][65];
    __shared__ float sm[64], sr[64];
    int nchunks = HW >> 6;
    int b  = blockIdx.x / nchunks;
    int p0 = (blockIdx.x % nchunks) << 6;
    int tid = threadIdx.x;
    if (tid < 64) {
        float s = 0.f, s2 = 0.f;
#pragma unroll
        for (int k = 0; k < 8; ++k) {
            s  += stats[k * 128 + tid];
            s2 += stats[k * 128 + 64 + tid];
        }
        float mean = s * invN;
        float var  = s2 * invN - mean * mean;
        sm[tid] = mean;
        sr[tid] = rsqrtf(var + 1e-5f);
    }
    __syncthreads();
#pragma unroll
    for (int it = 0; it < 2; ++it) {
        int item = it * 256 + tid;
        int p = item >> 3, c0 = (item & 7) * 8;
        size_t gi = ((size_t)(b * HW + p0 + p)) * 64 + c0;
        bf16x8_t v = *(const bf16x8_t*)&in[gi];
        bf16x8_t o;
#pragma unroll
        for (int j = 0; j < 8; ++j) {
            float f = (bf16_to_f((unsigned short)v[j]) - sm[c0 + j]) * sr[c0 + j];
            f = f > 0.f ? f : 0.f;
            ftile[p][c0 + j] = f;
            o[j] = f_to_bf16(f);
        }
        *(bf16x8_t*)&outh[gi] = o;
    }
    __syncthreads();
#pragma unroll
    for (int rep = 0; rep < 16; ++rep) {
        int item = rep * 256 + tid;
        int c = item >> 6, p = item & 63;
        out[((size_t)b * 64 + c) * HW + p0 + p] = ftile[p][c];
    }
}

// ------------------------------------------------- offset2/3: MFMA conv, N=18
__global__ __launch_bounds__(256, 1) void offconv_mfma_kernel(
    const short* __restrict__ xh,
    const short* __restrict__ wt,
    const float* __restrict__ bias,
    float* __restrict__ out,
    int H, int W, int Ho, int Wo)
{
    const int HW = Ho * Wo;
    const int tid = threadIdx.x;
    const int wv = tid >> 6, l = tid & 63;
    const int l15 = l & 15, lg = l >> 4;
    const int pix0 = blockIdx.x * 64 + wv * 16;
    const int b = pix0 / HW;
    const int r0 = pix0 - b * HW;

    int rp = r0 + l15;
    int ho = rp / Wo, wo = rp % Wo;
    const short* xb = xh + (size_t)b * H * W * 64;

    f32x4_t acc[2];
    acc[0] = (f32x4_t){0.f, 0.f, 0.f, 0.f};
    acc[1] = (f32x4_t){0.f, 0.f, 0.f, 0.f};

#pragma unroll 2
    for (int kc = 0; kc < 18; ++kc) {
        int tap = kc >> 1;
        int iy = ho * 2 - 1 + tap / 3;
        int ix = wo * 2 - 1 + tap % 3;
        bf16x8_t af = {};
        if (iy >= 0 && iy < H && ix >= 0 && ix < W)
            af = *(const bf16x8_t*)&xb[((size_t)iy * W + ix) * 64
                                       + (kc & 1) * 32 + lg * 8];
#pragma unroll
        for (int nf = 0; nf < 2; ++nf) {
            bf16x8_t bf = *(const bf16x8_t*)(wt + (((size_t)(kc * 2 + nf)) * 64 + l) * 8);
            acc[nf] = __builtin_amdgcn_mfma_f32_16x16x32_bf16(af, bf, acc[nf], 0, 0, 0);
        }
    }

#pragma unroll
    for (int nf = 0; nf < 2; ++nf) {
        int oc = nf * 16 + l15;
        if (oc < 18) {
            float bv = bias[oc];
            f32x4_t v = acc[nf];
            v[0] += bv; v[1] += bv; v[2] += bv; v[3] += bv;
            *(f32x4_t*)&out[((size_t)(b * 18 + oc)) * HW + r0 + lg * 4] = v;
        }
    }
}

// ------------------------------------------------- deform1: fused offset1 +
// deform (C=3, MFMA MAC) + skip; x4 is bf16 NHWC4
__global__ __launch_bounds__(256, 1) void deform1_kernel(
    const unsigned short* __restrict__ x4,
    const float* __restrict__ wof,
    const float* __restrict__ bof,
    const short* __restrict__ wtd1,
    const float* __restrict__ bias,
    const float* __restrict__ pool,
    const float* __restrict__ wsk,
    const float* __restrict__ bsk,
    short* __restrict__ outh)
{
    const int H = 640, W = 640, Ho = 160, Wo = 160, HW = 25600;
    constexpr int P = 32;
    __shared__ float xtap[P * 9][4];
    __shared__ float swof[486];
    __shared__ float sbof[18];
    __shared__ float spool[3][P];
    __shared__ float off1[P][18];
    __shared__ alignas(16) short sampb[P][40];
    __shared__ int   sidx[P * 9][4];
    __shared__ float swt[P * 9][4];
    const int tid = threadIdx.x;
    const int pix0 = blockIdx.x * P;
    const int b = pix0 / HW;
    const int r0 = pix0 - b * HW;
    const unsigned short* xb = x4 + (size_t)b * H * W * 4;

    for (int item = tid; item < P * 9; item += TPB) {
        int p = item / 9, tap = item % 9;
        int r = r0 + p, ho = r / Wo, wo = r % Wo;
        int iy = ho * 4 - 1 + tap / 3;
        int ix = wo * 4 - 1 + tap % 3;
        f32x4_t s = (f32x4_t){0.f, 0.f, 0.f, 0.f};
        if (iy >= 0 && iy < H && ix >= 0 && ix < W) {
            u16x4_t u = *(const u16x4_t*)&xb[((size_t)iy * W + ix) * 4];
            s[0] = bf16_to_f(u[0]);
            s[1] = bf16_to_f(u[1]);
            s[2] = bf16_to_f(u[2]);
        }
        *(f32x4_t*)xtap[item] = s;
    }
    for (int i = tid; i < P * 40; i += TPB) ((short*)sampb)[i] = 0;
    for (int i = tid; i < 96; i += TPB) {
        int c = i >> 5, p = i & 31;
        spool[c][p] = pool[((size_t)(b * 3 + c)) * HW + r0 + p];
    }
    for (int item = tid; item < 486; item += TPB) swof[item] = wof[item];
    if (tid < 18) sbof[tid] = bof[tid];
    __syncthreads();

    for (int item = tid; item < P * 18; item += TPB) {
        int p = item / 18, o = item % 18;
        float acc = sbof[o];
#pragma unroll
        for (int tap = 0; tap < 9; ++tap) {
            const float* xt = xtap[p * 9 + tap];
#pragma unroll
            for (int c = 0; c < 3; ++c)
                acc += xt[c] * swof[(o * 3 + c) * 9 + tap];
        }
        off1[p][o] = acc;
    }
    __syncthreads();

    for (int item = tid; item < P * 9; item += TPB) {
        int p = item / 9, tap = item % 9;
        int r = r0 + p, ho = r / Wo, wo = r % Wo;
        float dy = off1[p][2 * tap];
        float dx = off1[p][2 * tap + 1];
        float ys = (float)(ho * 4 - 1 + tap / 3) + dy;
        float xs = (float)(wo * 4 - 1 + tap % 3) + dx;
        float y0f = floorf(ys), x0f = floorf(xs);
        float fy = ys - y0f, fx = xs - x0f;
        int y0 = (int)y0f, x0 = (int)x0f;
        float wts[4] = {(1.f - fy) * (1.f - fx), (1.f - fy) * fx,
                        fy * (1.f - fx),          fy * fx};
#pragma unroll
        for (int j = 0; j < 4; ++j) {
            int iy = y0 + (j >> 1), ix = x0 + (j & 1);
            bool v = (iy >= 0) && (iy < H) && (ix >= 0) && (ix < W);
            sidx[item][j] = v ? (iy * W + ix) : 0;
            swt[item][j]  = v ? wts[j] : 0.f;
        }
    }
    __syncthreads();

    for (int item = tid; item < P * 9; item += TPB) {
        int p = item / 9, tap = item % 9;
        i32x4_t id4 = *(const i32x4_t*)sidx[item];
        f32x4_t w4  = *(const f32x4_t*)swt[item];
        u16x4_t a0 = *(const u16x4_t*)&xb[(size_t)(unsigned)id4[0] * 4];
        u16x4_t a1 = *(const u16x4_t*)&xb[(size_t)(unsigned)id4[1] * 4];
        u16x4_t a2 = *(const u16x4_t*)&xb[(size_t)(unsigned)id4[2] * 4];
        u16x4_t a3 = *(const u16x4_t*)&xb[(size_t)(unsigned)id4[3] * 4];
        sampb[p][0 * 9 + tap] = f_to_bf16(
            w4[0]*bf16_to_f(a0[0]) + w4[1]*bf16_to_f(a1[0])
          + w4[2]*bf16_to_f(a2[0]) + w4[3]*bf16_to_f(a3[0]));
        sampb[p][1 * 9 + tap] = f_to_bf16(
            w4[0]*bf16_to_f(a0[1]) + w4[1]*bf16_to_f(a1[1])
          + w4[2]*bf16_to_f(a2[1]) + w4[3]*bf16_to_f(a3[1]));
        sampb[p][2 * 9 + tap] = f_to_bf16(
            w4[0]*bf16_to_f(a0[2]) + w4[1]*bf16_to_f(a1[2])
          + w4[2]*bf16_to_f(a2[2]) + w4[3]*bf16_to_f(a3[2]));
    }
    __syncthreads();

    const int wv = tid >> 6;
    const int l  = tid & 63;
    const int l15 = l & 15, lg = l >> 4;
    bf16x8_t bf  = *(const bf16x8_t*)(wtd1 + (((size_t)wv * 64 + l)) * 8);
    bf16x8_t af0 = *(const bf16x8_t*)&sampb[l15][lg * 8];
    bf16x8_t af1 = *(const bf16x8_t*)&sampb[l15 + 16][lg * 8];
    f32x4_t z = (f32x4_t){0.f, 0.f, 0.f, 0.f};
    f32x4_t acc0 = __builtin_amdgcn_mfma_f32_16x16x32_bf16(af0, bf, z, 0, 0, 0);
    f32x4_t acc1 = __builtin_amdgcn_mfma_f32_16x16x32_bf16(af1, bf, z, 0, 0, 0);

    int oc = wv * 16 + l15;
    float bb = bias[oc] + bsk[oc];
    float w0 = wsk[oc * 3 + 0], w1 = wsk[oc * 3 + 1], w2 = wsk[oc * 3 + 2];
    short* otile = (short*)xtap;
    __syncthreads();
#pragma unroll
    for (int mf = 0; mf < 2; ++mf) {
        f32x4_t a = mf ? acc1 : acc0;
#pragma unroll
        for (int k = 0; k < 4; ++k) {
            int px = mf * 16 + lg * 4 + k;
            float sv = w0 * spool[0][px] + w1 * spool[1][px] + w2 * spool[2][px];
            otile[px * 64 + oc] = f_to_bf16(a[k] + bb + sv);
        }
    }
    __syncthreads();
    {
        int c8 = tid & 7, px = tid >> 3;
        *(bf16x8_t*)&outh[((size_t)(b * HW + r0 + px)) * 64 + c8 * 8] =
            *(bf16x8_t*)&otile[px * 64 + c8 * 8];
    }
}

// ------------------------------------------------- deform MFMA: C=64 -> O
template <int O, int DUAL>
__global__ __launch_bounds__(256, 1) void deform_mfma_kernel(
    const short* __restrict__ xh,
    const float* __restrict__ off,
    const short* __restrict__ wt,
    const float* __restrict__ bias,
    float* __restrict__ out,
    short* __restrict__ outh,
    int H, int W, int Ho, int Wo, int stride)
{
    constexpr int NF = O / 64;
    constexpr int NFRAG = O / 16;
    constexpr int P  = 32;
    __shared__ alignas(16) short samp[P * 576];
    __shared__ int   sidx[P * 9][4];
    __shared__ float swt[P * 9][4];

    const int tid = threadIdx.x;
    const int HW = Ho * Wo;
    const int pix0 = blockIdx.x * P;
    const int b = pix0 / HW;
    const int r0 = pix0 - b * HW;

    for (int item = tid; item < P * 9; item += TPB) {
        int p = item / 9, tap = item % 9;
        int r = r0 + p, ho = r / Wo, wo = r % Wo;
        float dy = off[((size_t)(b * 18 + 2 * tap) * Ho + ho) * Wo + wo];
        float dx = off[((size_t)(b * 18 + 2 * tap + 1) * Ho + ho) * Wo + wo];
        float ys = (float)(ho * stride - 1 + tap / 3) + dy;
        float xs = (float)(wo * stride - 1 + tap % 3) + dx;
        float y0f = floorf(ys), x0f = floorf(xs);
        float fy = ys - y0f, fx = xs - x0f;
        int y0 = (int)y0f, x0 = (int)x0f;
        float wts[4] = {(1.f - fy) * (1.f - fx), (1.f - fy) * fx,
                        fy * (1.f - fx),          fy * fx};
#pragma unroll
        for (int j = 0; j < 4; ++j) {
            int iy = y0 + (j >> 1), ix = x0 + (j & 1);
            bool v = (iy >= 0) && (iy < H) && (ix >= 0) && (ix < W);
            sidx[item][j] = v ? (iy * W + ix) : 0;
            swt[item][j]  = v ? wts[j] : 0.f;
        }
    }
    __syncthreads();

    {
        const int p  = tid >> 3;
        const int ic = (tid & 7) * 8;
        const int swc = (ic >> 3) ^ (p & 7);
        const short* xb = xh + (size_t)b * H * W * 64;
#pragma unroll 3
        for (int tap = 0; tap < 9; ++tap) {
            int e = p * 9 + tap;
            i32x4_t id4 = *(const i32x4_t*)sidx[e];
            f32x4_t w4  = *(const f32x4_t*)swt[e];
            u16x8_t u0 = *(const u16x8_t*)&xb[(size_t)(unsigned)id4[0] * 64 + ic];
            u16x8_t u1 = *(const u16x8_t*)&xb[(size_t)(unsigned)id4[1] * 64 + ic];
            u16x8_t u2 = *(const u16x8_t*)&xb[(size_t)(unsigned)id4[2] * 64 + ic];
            u16x8_t u3 = *(const u16x8_t*)&xb[(size_t)(unsigned)id4[3] * 64 + ic];
            bf16x8_t o;
#pragma unroll
            for (int j = 0; j < 8; ++j) {
                float v = w4[0]*bf16_to_f(u0[j]) + w4[1]*bf16_to_f(u1[j])
                        + w4[2]*bf16_to_f(u2[j]) + w4[3]*bf16_to_f(u3[j]);
                o[j] = f_to_bf16(v);
            }
            *(bf16x8_t*)&samp[p * 576 + (tap * 8 + swc) * 8] = o;
        }
    }
    __syncthreads();

    const int wv = tid >> 6;
    const int l  = tid & 63;
    const int l15 = l & 15, lg = l >> 4;
    f32x4_t acc[2][NF];
#pragma unroll
    for (int mf = 0; mf < 2; ++mf)
#pragma unroll
        for (int nf = 0; nf < NF; ++nf)
            acc[mf][nf] = (f32x4_t){0.f, 0.f, 0.f, 0.f};

#pragma unroll 2
    for (int kc = 0; kc < 18; ++kc) {
        int tap = kc >> 1;
        int low = (((kc & 1) << 2) | lg) ^ (l15 & 7);
        bf16x8_t af0 = *(const bf16x8_t*)&samp[l15 * 576 + (tap * 8 + low) * 8];
        bf16x8_t af1 = *(const bf16x8_t*)&samp[(l15 + 16) * 576 + (tap * 8 + low) * 8];
#pragma unroll
        for (int nf = 0; nf < NF; ++nf) {
            int ocf = wv * NF + nf;
            bf16x8_t bf = *(const bf16x8_t*)(wt + (((size_t)(kc * NFRAG + ocf)) * 64 + l) * 8);
            acc[0][nf] = __builtin_amdgcn_mfma_f32_16x16x32_bf16(af0, bf, acc[0][nf], 0, 0, 0);
            acc[1][nf] = __builtin_amdgcn_mfma_f32_16x16x32_bf16(af1, bf, acc[1][nf], 0, 0, 0);
        }
    }

#pragma unroll
    for (int mf = 0; mf < 2; ++mf)
#pragma unroll
        for (int nf = 0; nf < NF; ++nf) {
            int oc = (wv * NF + nf) * 16 + l15;
            float bv = bias[oc];
            f32x4_t v = acc[mf][nf];
            v[0] += bv; v[1] += bv; v[2] += bv; v[3] += bv;
            acc[mf][nf] = v;
            *(f32x4_t*)&out[((size_t)(b * O + oc)) * HW + r0 + mf * 16 + lg * 4] = v;
        }

    if (DUAL) {
        __syncthreads();
        short* otile = samp;
#pragma unroll
        for (int mf = 0; mf < 2; ++mf) {
            int oc = wv * 16 + l15;
#pragma unroll
            for (int k = 0; k < 4; ++k) {
                int px = mf * 16 + lg * 4 + k;
                otile[px * 64 + oc] = f_to_bf16(acc[mf][0][k]);
            }
        }
        __syncthreads();
        int c8 = tid & 7, px = tid >> 3;
        *(bf16x8_t*)&outh[((size_t)(b * HW + r0 + px)) * 64 + c8 * 8] =
            *(bf16x8_t*)&otile[px * 64 + c8 * 8];
    }
}

// ---------------------------------------------------------------- launch
extern "C" void kernel_launch(void* const* d_in, const int* in_sizes, int n_in,
                              void* d_out, int out_size, void* d_ws, size_t ws_size,
                              hipStream_t stream)
{
    const float* x      = (const float*)d_in[0];
    const float* w_off1 = (const float*)d_in[1];
    const float* b_off1 = (const float*)d_in[2];
    const float* w_d1   = (const float*)d_in[3];
    const float* b_d1   = (const float*)d_in[4];
    const float* w_skip = (const float*)d_in[5];
    const float* b_skip = (const float*)d_in[6];
    const float* w_bl1  = (const float*)d_in[7];
    const float* w_bl2  = (const float*)d_in[8];
    const float* w_off2 = (const float*)d_in[9];
    const float* b_off2 = (const float*)d_in[10];
    const float* w_d2   = (const float*)d_in[11];
    const float* b_d2   = (const float*)d_in[12];
    const float* w_off3 = (const float*)d_in[13];
    const float* b_off3 = (const float*)d_in[14];
    const float* w_d3   = (const float*)d_in[15];
    const float* b_d3   = (const float*)d_in[16];

    const int B = 8;
    float* A     = (float*)d_ws;
    float* bufB  = A + 3686400;
    float* bufC  = bufB + 13107200;

    short* hB   = (short*)bufB;
    short* hC   = (short*)bufC;
    float* pool = bufB + 8000000;

    short* wt1    = (short*)(A + 1000000);
    short* wt2    = wt1 + 18 * 4 * 512;
    short* wtd2   = (short*)(A + 1500000);
    short* wtd3   = (short*)(A + 1550000);
    short* wtoff2 = (short*)(A + 1700000);
    short* wtoff3 = (short*)(A + 1712000);
    short* wtd1   = (short*)(A + 1750000);
    float* stats1 = A + 1800000;
    float* stats2 = stats1 + 1024;
    float* zpage  = stats1 + 2048;

    float* out0 = (float*)d_out;
    float* out1 = out0 + 13107200;
    float* out2 = out1 + 3276800;

    const float invN = 1.0f / (B * 25600);

    prep_kernel<<<(8 * 25600 + TPB - 1) / TPB, TPB, 0, stream>>>(
        x, (unsigned short*)bufC, pool);

    repack_all_kernel<<<(299520 + TPB - 1) / TPB, TPB, 0, stream>>>(
        w_bl1, wt1, w_bl2, wt2, w_d2, wtd2, w_d3, wtd3,
        w_off2, wtoff2, w_off3, wtoff3, w_d1, wtd1, stats1);

    deform1_kernel<<<8 * 25600 / 32, TPB, 0, stream>>>(
        (const unsigned short*)bufC, w_off1, b_off1, wtd1, b_d1,
        pool, w_skip, b_skip, hB);

    conv3x3_mfma_kernel<0><<<800, TPB, 0, stream>>>(
        hB, wt1, hC, stats1, nullptr, invN, zpage);

    conv3x3_mfma_kernel<1><<<800, TPB, 0, stream>>>(
        hC, wt2, hB, stats2, stats1, invN, zpage);

    bn_apply_dual_kernel<<<8 * 400, TPB, 0, stream>>>(
        hB, stats2, out0, hC, 25600, invN);

    offconv_mfma_kernel<<<8 * 6400 / 64, TPB, 0, stream>>>(
        hC, wtoff2, b_off2, A, 160, 160, 80, 80);

    deform_mfma_kernel<64, 1><<<8 * 6400 / 32, TPB, 0, stream>>>(
        hC, A, wtd2, b_d2, out1, hB, 160, 160, 80, 80, 2);

    offconv_mfma_kernel<<<8 * 1600 / 64, TPB, 0, stream>>>(
        hB, wtoff3, b_off3, A, 80, 80, 40, 40);

    deform_mfma_kernel<256, 0><<<8 * 1600 / 32, TPB, 0, stream>>>(
        hB, A, wtd3, b_d3, out2, nullptr, 80, 80, 40, 40, 2);
}

// Round 23
// 205.594 us; speedup vs baseline: 1.1056x; 1.0004x over previous
//
#include <hip/hip_runtime.h>
#include <hip/hip_bf16.h>
#include <math.h>

#define TPB 256

typedef __attribute__((ext_vector_type(8))) short bf16x8_t;
typedef __attribute__((ext_vector_type(4))) float f32x4_t;
typedef __attribute__((ext_vector_type(4))) int i32x4_t;
typedef __attribute__((ext_vector_type(4))) unsigned short u16x4_t;
typedef __attribute__((ext_vector_type(8))) unsigned short u16x8_t;

#if defined(__has_builtin)
#if __has_builtin(__builtin_amdgcn_global_load_lds)
#define HAS_GLOAD_LDS 1
#endif
#endif

static __device__ __forceinline__ float bf16_to_f(unsigned short s) {
    union { unsigned u; float f; } cv;
    cv.u = ((unsigned)s) << 16;
    return cv.f;
}
static __device__ __forceinline__ short f_to_bf16(float v) {
    __hip_bfloat16 h = __float2bfloat16(v);
    return *(short*)&h;
}

// ------------------------------------------------- prep: x NCHW -> x4 NHWC4 bf16 + pool
__global__ void prep_kernel(const float* __restrict__ in,
                            unsigned short* __restrict__ x4,
                            float* __restrict__ pool)
{
    const int HWo = 25600, H = 640, W = 640;
    int idx = blockIdx.x * TPB + threadIdx.x;
    if (idx >= 8 * HWo) return;
    int b = idx / HWo, r = idx % HWo;
    int ho = r / 160, wo = r % 160;
    float s0 = 0.f, s1 = 0.f, s2 = 0.f;
    unsigned short* x4b = x4 + (size_t)b * H * W * 4;
#pragma unroll
    for (int dy = 0; dy < 4; ++dy) {
        int row = ho * 4 + dy;
        size_t base = ((size_t)row * W + wo * 4);
        f32x4_t a0 = *(const f32x4_t*)&in[((size_t)(b * 3 + 0) * H * W) + base];
        f32x4_t a1 = *(const f32x4_t*)&in[((size_t)(b * 3 + 1) * H * W) + base];
        f32x4_t a2 = *(const f32x4_t*)&in[((size_t)(b * 3 + 2) * H * W) + base];
        s0 += a0[0] + a0[1] + a0[2] + a0[3];
        s1 += a1[0] + a1[1] + a1[2] + a1[3];
        s2 += a2[0] + a2[1] + a2[2] + a2[3];
#pragma unroll
        for (int dx = 0; dx < 4; ++dx) {
            u16x4_t v;
            v[0] = (unsigned short)f_to_bf16(a0[dx]);
            v[1] = (unsigned short)f_to_bf16(a1[dx]);
            v[2] = (unsigned short)f_to_bf16(a2[dx]);
            v[3] = 0;
            *(u16x4_t*)&x4b[(base + dx) * 4] = v;
        }
    }
    pool[((size_t)(b * 3 + 0)) * HWo + r] = s0 * (1.0f / 16.0f);
    pool[((size_t)(b * 3 + 1)) * HWo + r] = s1 * (1.0f / 16.0f);
    pool[((size_t)(b * 3 + 2)) * HWo + r] = s2 * (1.0f / 16.0f);
}

// ------------------------------------------------- single repack-everything kernel
static __device__ __forceinline__ void repack_one(
    const float* __restrict__ w, short* __restrict__ wtf,
    int idx, int Oreal, int NFRAG)
{
    int j    = idx & 7;
    int lane = (idx >> 3) & 63;
    int t    = idx >> 9;
    int ocf  = t % NFRAG;
    int kc   = t / NFRAG;
    int oc   = ocf * 16 + (lane & 15);
    int tap  = kc >> 1;
    int ic   = (kc & 1) * 32 + (lane >> 4) * 8 + j;
    float v = 0.f;
    if (oc < Oreal)
        v = w[((size_t)(oc * 64 + ic)) * 9 + tap];
    wtf[idx] = f_to_bf16(v);
}

__global__ void repack_all_kernel(
    const float* __restrict__ w_bl1, short* __restrict__ wt1,
    const float* __restrict__ w_bl2, short* __restrict__ wt2,
    const float* __restrict__ w_d2,  short* __restrict__ wtd2,
    const float* __restrict__ w_d3,  short* __restrict__ wtd3,
    const float* __restrict__ w_off2, short* __restrict__ wtoff2,
    const float* __restrict__ w_off3, short* __restrict__ wtoff3,
    const float* __restrict__ w_d1,  short* __restrict__ wtd1,
    float* __restrict__ stats)
{
    int idx = blockIdx.x * TPB + threadIdx.x;
    if (idx < 36864) { repack_one(w_bl1, wt1, idx, 64, 4); return; }
    idx -= 36864;
    if (idx < 36864) { repack_one(w_bl2, wt2, idx, 64, 4); return; }
    idx -= 36864;
    if (idx < 36864) { repack_one(w_d2, wtd2, idx, 64, 4); return; }
    idx -= 36864;
    if (idx < 147456) { repack_one(w_d3, wtd3, idx, 256, 16); return; }
    idx -= 147456;
    if (idx < 18432) { repack_one(w_off2, wtoff2, idx, 18, 2); return; }
    idx -= 18432;
    if (idx < 18432) { repack_one(w_off3, wtoff3, idx, 18, 2); return; }
    idx -= 18432;
    if (idx < 2048) {
        int j = idx & 7, lane = (idx >> 3) & 63, ocf = idx >> 9;
        int oc = ocf * 16 + (lane & 15);
        int k  = (lane >> 4) * 8 + j;
        float v = 0.f;
        if (k < 27) v = w_d1[(size_t)oc * 27 + k];
        wtd1[idx] = f_to_bf16(v);
        return;
    }
    idx -= 2048;
    if (idx < 2560) stats[idx] = 0.f;
}

// ------------------------------------------------- MFMA conv 3x3 (64->64, s1)
template <int NORM>
__global__ __launch_bounds__(256, 2) void conv3x3_mfma_kernel(
    const short* __restrict__ xh,
    const short* __restrict__ wt,
    short* __restrict__ outh,
    float* __restrict__ stats,
    const float* __restrict__ stats_in,
    float invN,
    const float* __restrict__ zp)
{
    __shared__ short tile[2816 * 8];
    __shared__ float sstat[128];
    __shared__ float sm[64], sr[64];
    const int H = 160, W = 160, HW = 25600;
    int blk = blockIdx.x;
    int b  = blk / 100;
    int r  = blk % 100;
    int y0 = (r / 10) * 16;
    int x0 = (r % 10) * 16;
    const int tid = threadIdx.x;
    const short* inb = xh + (size_t)b * HW * 64;

    if (tid < 128) sstat[tid] = 0.f;
    if (NORM) {
        if (tid < 64) {
            float s = 0.f, s2 = 0.f;
#pragma unroll
            for (int k = 0; k < 8; ++k) {
                s  += stats_in[k * 128 + tid];
                s2 += stats_in[k * 128 + 64 + tid];
            }
            float mean = s * invN;
            float var  = s2 * invN - mean * mean;
            sm[tid] = mean;
            sr[tid] = rsqrtf(var + 1e-5f);
        }
        __syncthreads();
    }

    if (NORM == 0) {
#ifdef HAS_GLOAD_LDS
#pragma unroll
        for (int it = 0; it < 11; ++it) {
            int item = it * 256 + tid;
            int c8  = item & 7;
            int pix = item >> 3;
            int row = pix / 18;
            int col = pix - row * 18;
            int y = y0 + row - 1;
            int x = x0 + col - 1;
            bool ok = (pix < 324) & (y >= 0) & (y < H) & (x >= 0) & (x < W);
            int cs = c8 ^ (col & 7);
            const short* src = ok
                ? &inb[((size_t)y * W + x) * 64 + (cs << 3)]
                : (const short*)zp;
            __builtin_amdgcn_global_load_lds(
                (const __attribute__((address_space(1))) unsigned int*)src,
                (__attribute__((address_space(3))) unsigned int*)
                    &tile[(it * 256 + (tid & 192)) * 8],
                16, 0, 0);
        }
#else
#pragma unroll
        for (int it = 0; it < 11; ++it) {
            int item = it * 256 + tid;
            int c8  = item & 7;
            int pix = item >> 3;
            int row = pix / 18;
            int col = pix - row * 18;
            int y = y0 + row - 1;
            int x = x0 + col - 1;
            bool ok = (pix < 324) & (y >= 0) & (y < H) & (x >= 0) & (x < W);
            int cs = c8 ^ (col & 7);
            const short* src = ok
                ? &inb[((size_t)y * W + x) * 64 + (cs << 3)]
                : (const short*)zp;
            *(bf16x8_t*)&tile[item * 8] = *(const bf16x8_t*)src;
        }
#endif
    } else {
#pragma unroll
        for (int it = 0; it < 11; ++it) {
            int item = it * 256 + tid;
            int c8  = item & 7;
            int pix = item >> 3;
            int row = pix / 18;
            int col = pix - row * 18;
            int y = y0 + row - 1;
            int x = x0 + col - 1;
            bool ok = (pix < 324) & (y >= 0) & (y < H) & (x >= 0) & (x < W);
            int cs = c8 ^ (col & 7);
            const short* src = ok
                ? &inb[((size_t)y * W + x) * 64 + (cs << 3)]
                : (const short*)zp;
            bf16x8_t v = *(const bf16x8_t*)src;
            int cs8 = cs << 3;
            bf16x8_t o;
#pragma unroll
            for (int j = 0; j < 8; ++j) {
                float f = (bf16_to_f((unsigned short)v[j]) - sm[cs8 + j]) * sr[cs8 + j];
                f = f > 0.f ? f : 0.f;
                o[j] = ok ? f_to_bf16(f) : (short)0;
            }
            *(bf16x8_t*)&tile[item * 8] = o;
        }
    }
    __syncthreads();

    const int wv  = tid >> 6;
    const int l   = tid & 63;
    const int l15 = l & 15;
    const int lg  = l >> 4;

    f32x4_t acc[4][4];
#pragma unroll
    for (int i = 0; i < 4; ++i)
#pragma unroll
        for (int j = 0; j < 4; ++j)
            acc[i][j] = (f32x4_t){0.f, 0.f, 0.f, 0.f};

    bf16x8_t bfp[2][4], afp[2][4];
#pragma unroll
    for (int nf = 0; nf < 4; ++nf)
        bfp[0][nf] = *(const bf16x8_t*)(wt + (((size_t)(0 * 4 + nf)) * 64 + l) * 8);
    {
        int colr = l15;
        int chunk = lg ^ (colr & 7);
#pragma unroll
        for (int mf = 0; mf < 4; ++mf)
            afp[0][mf] = *(const bf16x8_t*)&tile[((wv * 4 + mf) * 18 + colr) * 64 + chunk * 8];
    }
#pragma unroll
    for (int kc = 0; kc < 18; ++kc) {
        const int cur = kc & 1, nxt = cur ^ 1;
        if (kc + 1 < 18) {
            int kn = kc + 1;
#pragma unroll
            for (int nf = 0; nf < 4; ++nf)
                bfp[nxt][nf] = *(const bf16x8_t*)(wt + (((size_t)(kn * 4 + nf)) * 64 + l) * 8);
            int tap = kn >> 1;
            int dy = tap / 3, dx = tap % 3;
            int colr = l15 + dx;
            int chunk = (((kn & 1) << 2) + lg) ^ (colr & 7);
#pragma unroll
            for (int mf = 0; mf < 4; ++mf)
                afp[nxt][mf] = *(const bf16x8_t*)&tile[((wv * 4 + mf + dy) * 18 + colr) * 64 + chunk * 8];
        }
#pragma unroll
        for (int mf = 0; mf < 4; ++mf)
#pragma unroll
            for (int nf = 0; nf < 4; ++nf)
                acc[mf][nf] = __builtin_amdgcn_mfma_f32_16x16x32_bf16(
                    afp[cur][mf], bfp[cur][nf], acc[mf][nf], 0, 0, 0);
    }

    __syncthreads();
#pragma unroll
    for (int mf = 0; mf < 4; ++mf) {
        int py = wv * 4 + mf;
#pragma unroll
        for (int nf = 0; nf < 4; ++nf) {
            int oc = nf * 16 + l15;
#pragma unroll
            for (int k = 0; k < 4; ++k)
                tile[((py * 16) + lg * 4 + k) * 64 + oc] = f_to_bf16(acc[mf][nf][k]);
        }
    }
    __syncthreads();
    short* outb = outh + (size_t)b * HW * 64;
#pragma unroll
    for (int j = 0; j < 8; ++j) {
        int item = j * 256 + tid;
        int c8  = item & 7;
        int pix = item >> 3;
        int py  = pix >> 4, px = pix & 15;
        *(bf16x8_t*)&outb[((size_t)(y0 + py) * W + x0 + px) * 64 + c8 * 8] =
            *(bf16x8_t*)&tile[pix * 64 + c8 * 8];
    }

#pragma unroll
    for (int nf = 0; nf < 4; ++nf) {
        float s = 0.f, s2 = 0.f;
#pragma unroll
        for (int mf = 0; mf < 4; ++mf)
#pragma unroll
            for (int k = 0; k < 4; ++k) {
                float v = acc[mf][nf][k];
                s += v; s2 += v * v;
            }
        s  += __shfl_xor(s, 16, 64);  s  += __shfl_xor(s, 32, 64);
        s2 += __shfl_xor(s2, 16, 64); s2 += __shfl_xor(s2, 32, 64);
        if (lg == 0) {
            int oc = nf * 16 + l15;
            atomicAdd(&sstat[oc], s);
            atomicAdd(&sstat[64 + oc], s2);
        }
    }
    __syncthreads();
    float* st = stats + (size_t)(blockIdx.x & 7) * 128;
    if (tid < 128) atomicAdd(&st[tid], sstat[tid]);
}

// ------------------------------------------------- BN apply dual
__global__ void bn_apply_dual_kernel(const short* __restrict__ in,
                                     const float* __restrict__ stats,
                                     float* __restrict__ out,
                                     short* __restrict__ outh,
                                     int HW, float invN)
{
    __shared__ float ftile[64][65];
    __shared__ float sm[64], sr[64];
    int nchunks = HW >> 6;
    int b  = blockIdx.x / nchunks;
    int p0 = (blockIdx.x % nchunks) << 6;
    int tid = threadIdx.x;
    if (tid < 64) {
        float s = 0.f, s2 = 0.f;
#pragma unroll
        for (int k = 0; k < 8; ++k) {
            s  += stats[k * 128 + tid];
            s2 += stats[k * 128 + 64 + tid];
        }
        float mean = s * invN;
        float var  = s2 * invN - mean * mean;
        sm[tid] = mean;
        sr[tid] = rsqrtf(var + 1e-5f);
    }
    __syncthreads();
#pragma unroll
    for (int it = 0; it < 2; ++it) {
        int item = it * 256 + tid;
        int p = item >> 3, c0 = (item & 7) * 8;
        size_t gi = ((size_t)(b * HW + p0 + p)) * 64 + c0;
        bf16x8_t v = *(const bf16x8_t*)&in[gi];
        bf16x8_t o;
#pragma unroll
        for (int j = 0; j < 8; ++j) {
            float f = (bf16_to_f((unsigned short)v[j]) - sm[c0 + j]) * sr[c0 + j];
            f = f > 0.f ? f : 0.f;
            ftile[p][c0 + j] = f;
            o[j] = f_to_bf16(f);
        }
        *(bf16x8_t*)&outh[gi] = o;
    }
    __syncthreads();
#pragma unroll
    for (int rep = 0; rep < 16; ++rep) {
        int item = rep * 256 + tid;
        int c = item >> 6, p = item & 63;
        out[((size_t)b * 64 + c) * HW + p0 + p] = ftile[p][c];
    }
}

// ------------------------------------------------- offset2/3: MFMA conv, N=18
__global__ __launch_bounds__(256, 1) void offconv_mfma_kernel(
    const short* __restrict__ xh,
    const short* __restrict__ wt,
    const float* __restrict__ bias,
    float* __restrict__ out,
    int H, int W, int Ho, int Wo)
{
    const int HW = Ho * Wo;
    const int tid = threadIdx.x;
    const int wv = tid >> 6, l = tid & 63;
    const int l15 = l & 15, lg = l >> 4;
    const int pix0 = blockIdx.x * 64 + wv * 16;
    const int b = pix0 / HW;
    const int r0 = pix0 - b * HW;

    int rp = r0 + l15;
    int ho = rp / Wo, wo = rp % Wo;
    const short* xb = xh + (size_t)b * H * W * 64;

    f32x4_t acc[2];
    acc[0] = (f32x4_t){0.f, 0.f, 0.f, 0.f};
    acc[1] = (f32x4_t){0.f, 0.f, 0.f, 0.f};

#pragma unroll 2
    for (int kc = 0; kc < 18; ++kc) {
        int tap = kc >> 1;
        int iy = ho * 2 - 1 + tap / 3;
        int ix = wo * 2 - 1 + tap % 3;
        bf16x8_t af = {};
        if (iy >= 0 && iy < H && ix >= 0 && ix < W)
            af = *(const bf16x8_t*)&xb[((size_t)iy * W + ix) * 64
                                       + (kc & 1) * 32 + lg * 8];
#pragma unroll
        for (int nf = 0; nf < 2; ++nf) {
            bf16x8_t bf = *(const bf16x8_t*)(wt + (((size_t)(kc * 2 + nf)) * 64 + l) * 8);
            acc[nf] = __builtin_amdgcn_mfma_f32_16x16x32_bf16(af, bf, acc[nf], 0, 0, 0);
        }
    }

#pragma unroll
    for (int nf = 0; nf < 2; ++nf) {
        int oc = nf * 16 + l15;
        if (oc < 18) {
            float bv = bias[oc];
            f32x4_t v = acc[nf];
            v[0] += bv; v[1] += bv; v[2] += bv; v[3] += bv;
            *(f32x4_t*)&out[((size_t)(b * 18 + oc)) * HW + r0 + lg * 4] = v;
        }
    }
}

// ------------------------------------------------- deform1: fused offset1 +
// deform (C=3, MFMA MAC) + skip; x4 is bf16 NHWC4
__global__ __launch_bounds__(256, 1) void deform1_kernel(
    const unsigned short* __restrict__ x4,
    const float* __restrict__ wof,
    const float* __restrict__ bof,
    const short* __restrict__ wtd1,
    const float* __restrict__ bias,
    const float* __restrict__ pool,
    const float* __restrict__ wsk,
    const float* __restrict__ bsk,
    short* __restrict__ outh)
{
    const int H = 640, W = 640, Ho = 160, Wo = 160, HW = 25600;
    constexpr int P = 32;
    __shared__ float xtap[P * 9][4];
    __shared__ float swof[486];
    __shared__ float sbof[18];
    __shared__ float spool[3][P];
    __shared__ float off1[P][18];
    __shared__ alignas(16) short sampb[P][40];
    __shared__ int   sidx[P * 9][4];
    __shared__ float swt[P * 9][4];
    const int tid = threadIdx.x;
    const int pix0 = blockIdx.x * P;
    const int b = pix0 / HW;
    const int r0 = pix0 - b * HW;
    const unsigned short* xb = x4 + (size_t)b * H * W * 4;

    for (int item = tid; item < P * 9; item += TPB) {
        int p = item / 9, tap = item % 9;
        int r = r0 + p, ho = r / Wo, wo = r % Wo;
        int iy = ho * 4 - 1 + tap / 3;
        int ix = wo * 4 - 1 + tap % 3;
        f32x4_t s = (f32x4_t){0.f, 0.f, 0.f, 0.f};
        if (iy >= 0 && iy < H && ix >= 0 && ix < W) {
            u16x4_t u = *(const u16x4_t*)&xb[((size_t)iy * W + ix) * 4];
            s[0] = bf16_to_f(u[0]);
            s[1] = bf16_to_f(u[1]);
            s[2] = bf16_to_f(u[2]);
        }
        *(f32x4_t*)xtap[item] = s;
    }
    for (int i = tid; i < P * 40; i += TPB) ((short*)sampb)[i] = 0;
    for (int i = tid; i < 96; i += TPB) {
        int c = i >> 5, p = i & 31;
        spool[c][p] = pool[((size_t)(b * 3 + c)) * HW + r0 + p];
    }
    for (int item = tid; item < 486; item += TPB) swof[item] = wof[item];
    if (tid < 18) sbof[tid] = bof[tid];
    __syncthreads();

    for (int item = tid; item < P * 18; item += TPB) {
        int p = item / 18, o = item % 18;
        float acc = sbof[o];
#pragma unroll
        for (int tap = 0; tap < 9; ++tap) {
            const float* xt = xtap[p * 9 + tap];
#pragma unroll
            for (int c = 0; c < 3; ++c)
                acc += xt[c] * swof[(o * 3 + c) * 9 + tap];
        }
        off1[p][o] = acc;
    }
    __syncthreads();

    for (int item = tid; item < P * 9; item += TPB) {
        int p = item / 9, tap = item % 9;
        int r = r0 + p, ho = r / Wo, wo = r % Wo;
        float dy = off1[p][2 * tap];
        float dx = off1[p][2 * tap + 1];
        float ys = (float)(ho * 4 - 1 + tap / 3) + dy;
        float xs = (float)(wo * 4 - 1 + tap % 3) + dx;
        float y0f = floorf(ys), x0f = floorf(xs);
        float fy = ys - y0f, fx = xs - x0f;
        int y0 = (int)y0f, x0 = (int)x0f;
        float wts[4] = {(1.f - fy) * (1.f - fx), (1.f - fy) * fx,
                        fy * (1.f - fx),          fy * fx};
#pragma unroll
        for (int j = 0; j < 4; ++j) {
            int iy = y0 + (j >> 1), ix = x0 + (j & 1);
            bool v = (iy >= 0) && (iy < H) && (ix >= 0) && (ix < W);
            sidx[item][j] = v ? (iy * W + ix) : 0;
            swt[item][j]  = v ? wts[j] : 0.f;
        }
    }
    __syncthreads();

    for (int item = tid; item < P * 9; item += TPB) {
        int p = item / 9, tap = item % 9;
        i32x4_t id4 = *(const i32x4_t*)sidx[item];
        f32x4_t w4  = *(const f32x4_t*)swt[item];
        u16x4_t a0 = *(const u16x4_t*)&xb[(size_t)(unsigned)id4[0] * 4];
        u16x4_t a1 = *(const u16x4_t*)&xb[(size_t)(unsigned)id4[1] * 4];
        u16x4_t a2 = *(const u16x4_t*)&xb[(size_t)(unsigned)id4[2] * 4];
        u16x4_t a3 = *(const u16x4_t*)&xb[(size_t)(unsigned)id4[3] * 4];
        sampb[p][0 * 9 + tap] = f_to_bf16(
            w4[0]*bf16_to_f(a0[0]) + w4[1]*bf16_to_f(a1[0])
          + w4[2]*bf16_to_f(a2[0]) + w4[3]*bf16_to_f(a3[0]));
        sampb[p][1 * 9 + tap] = f_to_bf16(
            w4[0]*bf16_to_f(a0[1]) + w4[1]*bf16_to_f(a1[1])
          + w4[2]*bf16_to_f(a2[1]) + w4[3]*bf16_to_f(a3[1]));
        sampb[p][2 * 9 + tap] = f_to_bf16(
            w4[0]*bf16_to_f(a0[2]) + w4[1]*bf16_to_f(a1[2])
          + w4[2]*bf16_to_f(a2[2]) + w4[3]*bf16_to_f(a3[2]));
    }
    __syncthreads();

    const int wv = tid >> 6;
    const int l  = tid & 63;
    const int l15 = l & 15, lg = l >> 4;
    bf16x8_t bf  = *(const bf16x8_t*)(wtd1 + (((size_t)wv * 64 + l)) * 8);
    bf16x8_t af0 = *(const bf16x8_t*)&sampb[l15][lg * 8];
    bf16x8_t af1 = *(const bf16x8_t*)&sampb[l15 + 16][lg * 8];
    f32x4_t z = (f32x4_t){0.f, 0.f, 0.f, 0.f};
    f32x4_t acc0 = __builtin_amdgcn_mfma_f32_16x16x32_bf16(af0, bf, z, 0, 0, 0);
    f32x4_t acc1 = __builtin_amdgcn_mfma_f32_16x16x32_bf16(af1, bf, z, 0, 0, 0);

    int oc = wv * 16 + l15;
    float bb = bias[oc] + bsk[oc];
    float w0 = wsk[oc * 3 + 0], w1 = wsk[oc * 3 + 1], w2 = wsk[oc * 3 + 2];
    short* otile = (short*)xtap;
    __syncthreads();
#pragma unroll
    for (int mf = 0; mf < 2; ++mf) {
        f32x4_t a = mf ? acc1 : acc0;
#pragma unroll
        for (int k = 0; k < 4; ++k) {
            int px = mf * 16 + lg * 4 + k;
            float sv = w0 * spool[0][px] + w1 * spool[1][px] + w2 * spool[2][px];
            otile[px * 64 + oc] = f_to_bf16(a[k] + bb + sv);
        }
    }
    __syncthreads();
    {
        int c8 = tid & 7, px = tid >> 3;
        *(bf16x8_t*)&outh[((size_t)(b * HW + r0 + px)) * 64 + c8 * 8] =
            *(bf16x8_t*)&otile[px * 64 + c8 * 8];
    }
}

// ------------------------------------------------- deform MFMA: C=64 -> O
template <int O, int DUAL>
__global__ __launch_bounds__(256, 1) void deform_mfma_kernel(
    const short* __restrict__ xh,
    const float* __restrict__ off,
    const short* __restrict__ wt,
    const float* __restrict__ bias,
    float* __restrict__ out,
    short* __restrict__ outh,
    int H, int W, int Ho, int Wo, int stride)
{
    constexpr int NF = O / 64;
    constexpr int NFRAG = O / 16;
    constexpr int P  = 32;
    __shared__ alignas(16) short samp[P * 576];
    __shared__ int   sidx[P * 9][4];
    __shared__ float swt[P * 9][4];

    const int tid = threadIdx.x;
    const int HW = Ho * Wo;
    const int pix0 = blockIdx.x * P;
    const int b = pix0 / HW;
    const int r0 = pix0 - b * HW;

    for (int item = tid; item < P * 9; item += TPB) {
        int p = item / 9, tap = item % 9;
        int r = r0 + p, ho = r / Wo, wo = r % Wo;
        float dy = off[((size_t)(b * 18 + 2 * tap) * Ho + ho) * Wo + wo];
        float dx = off[((size_t)(b * 18 + 2 * tap + 1) * Ho + ho) * Wo + wo];
        float ys = (float)(ho * stride - 1 + tap / 3) + dy;
        float xs = (float)(wo * stride - 1 + tap % 3) + dx;
        float y0f = floorf(ys), x0f = floorf(xs);
        float fy = ys - y0f, fx = xs - x0f;
        int y0 = (int)y0f, x0 = (int)x0f;
        float wts[4] = {(1.f - fy) * (1.f - fx), (1.f - fy) * fx,
                        fy * (1.f - fx),          fy * fx};
#pragma unroll
        for (int j = 0; j < 4; ++j) {
            int iy = y0 + (j >> 1), ix = x0 + (j & 1);
            bool v = (iy >= 0) && (iy < H) && (ix >= 0) && (ix < W);
            sidx[item][j] = v ? (iy * W + ix) : 0;
            swt[item][j]  = v ? wts[j] : 0.f;
        }
    }
    __syncthreads();

    {
        const int p  = tid >> 3;
        const int ic = (tid & 7) * 8;
        const int swc = (ic >> 3) ^ (p & 7);
        const short* xb = xh + (size_t)b * H * W * 64;
#pragma unroll 3
        for (int tap = 0; tap < 9; ++tap) {
            int e = p * 9 + tap;
            i32x4_t id4 = *(const i32x4_t*)sidx[e];
            f32x4_t w4  = *(const f32x4_t*)swt[e];
            u16x8_t u0 = *(const u16x8_t*)&xb[(size_t)(unsigned)id4[0] * 64 + ic];
            u16x8_t u1 = *(const u16x8_t*)&xb[(size_t)(unsigned)id4[1] * 64 + ic];
            u16x8_t u2 = *(const u16x8_t*)&xb[(size_t)(unsigned)id4[2] * 64 + ic];
            u16x8_t u3 = *(const u16x8_t*)&xb[(size_t)(unsigned)id4[3] * 64 + ic];
            bf16x8_t o;
#pragma unroll
            for (int j = 0; j < 8; ++j) {
                float v = w4[0]*bf16_to_f(u0[j]) + w4[1]*bf16_to_f(u1[j])
                        + w4[2]*bf16_to_f(u2[j]) + w4[3]*bf16_to_f(u3[j]);
                o[j] = f_to_bf16(v);
            }
            *(bf16x8_t*)&samp[p * 576 + (tap * 8 + swc) * 8] = o;
        }
    }
    __syncthreads();

    const int wv = tid >> 6;
    const int l  = tid & 63;
    const int l15 = l & 15, lg = l >> 4;
    f32x4_t acc[2][NF];
#pragma unroll
    for (int mf = 0; mf < 2; ++mf)
#pragma unroll
        for (int nf = 0; nf < NF; ++nf)
            acc[mf][nf] = (f32x4_t){0.f, 0.f, 0.f, 0.f};

#pragma unroll 2
    for (int kc = 0; kc < 18; ++kc) {
        int tap = kc >> 1;
        int low = (((kc & 1) << 2) | lg) ^ (l15 & 7);
        bf16x8_t af0 = *(const bf16x8_t*)&samp[l15 * 576 + (tap * 8 + low) * 8];
        bf16x8_t af1 = *(const bf16x8_t*)&samp[(l15 + 16) * 576 + (tap * 8 + low) * 8];
#pragma unroll
        for (int nf = 0; nf < NF; ++nf) {
            int ocf = wv * NF + nf;
            bf16x8_t bf = *(const bf16x8_t*)(wt + (((size_t)(kc * NFRAG + ocf)) * 64 + l) * 8);
            acc[0][nf] = __builtin_amdgcn_mfma_f32_16x16x32_bf16(af0, bf, acc[0][nf], 0, 0, 0);
            acc[1][nf] = __builtin_amdgcn_mfma_f32_16x16x32_bf16(af1, bf, acc[1][nf], 0, 0, 0);
        }
    }

#pragma unroll
    for (int mf = 0; mf < 2; ++mf)
#pragma unroll
        for (int nf = 0; nf < NF; ++nf) {
            int oc = (wv * NF + nf) * 16 + l15;
            float bv = bias[oc];
            f32x4_t v = acc[mf][nf];
            v[0] += bv; v[1] += bv; v[2] += bv; v[3] += bv;
            acc[mf][nf] = v;
            *(f32x4_t*)&out[((size_t)(b * O + oc)) * HW + r0 + mf * 16 + lg * 4] = v;
        }

    if (DUAL) {
        __syncthreads();
        short* otile = samp;
#pragma unroll
        for (int mf = 0; mf < 2; ++mf) {
            int oc = wv * 16 + l15;
#pragma unroll
            for (int k = 0; k < 4; ++k) {
                int px = mf * 16 + lg * 4 + k;
                otile[px * 64 + oc] = f_to_bf16(acc[mf][0][k]);
            }
        }
        __syncthreads();
        int c8 = tid & 7, px = tid >> 3;
        *(bf16x8_t*)&outh[((size_t)(b * HW + r0 + px)) * 64 + c8 * 8] =
            *(bf16x8_t*)&otile[px * 64 + c8 * 8];
    }
}

// ---------------------------------------------------------------- launch
extern "C" void kernel_launch(void* const* d_in, const int* in_sizes, int n_in,
                              void* d_out, int out_size, void* d_ws, size_t ws_size,
                              hipStream_t stream)
{
    const float* x      = (const float*)d_in[0];
    const float* w_off1 = (const float*)d_in[1];
    const float* b_off1 = (const float*)d_in[2];
    const float* w_d1   = (const float*)d_in[3];
    const float* b_d1   = (const float*)d_in[4];
    const float* w_skip = (const float*)d_in[5];
    const float* b_skip = (const float*)d_in[6];
    const float* w_bl1  = (const float*)d_in[7];
    const float* w_bl2  = (const float*)d_in[8];
    const float* w_off2 = (const float*)d_in[9];
    const float* b_off2 = (const float*)d_in[10];
    const float* w_d2   = (const float*)d_in[11];
    const float* b_d2   = (const float*)d_in[12];
    const float* w_off3 = (const float*)d_in[13];
    const float* b_off3 = (const float*)d_in[14];
    const float* w_d3   = (const float*)d_in[15];
    const float* b_d3   = (const float*)d_in[16];

    const int B = 8;
    float* A     = (float*)d_ws;
    float* bufB  = A + 3686400;
    float* bufC  = bufB + 13107200;

    short* hB   = (short*)bufB;
    short* hC   = (short*)bufC;
    float* pool = bufB + 8000000;

    short* wt1    = (short*)(A + 1000000);
    short* wt2    = wt1 + 18 * 4 * 512;
    short* wtd2   = (short*)(A + 1500000);
    short* wtd3   = (short*)(A + 1550000);
    short* wtoff2 = (short*)(A + 1700000);
    short* wtoff3 = (short*)(A + 1712000);
    short* wtd1   = (short*)(A + 1750000);
    float* stats1 = A + 1800000;
    float* stats2 = stats1 + 1024;
    float* zpage  = stats1 + 2048;

    float* out0 = (float*)d_out;
    float* out1 = out0 + 13107200;
    float* out2 = out1 + 3276800;

    const float invN = 1.0f / (B * 25600);

    prep_kernel<<<(8 * 25600 + TPB - 1) / TPB, TPB, 0, stream>>>(
        x, (unsigned short*)bufC, pool);

    repack_all_kernel<<<(299520 + TPB - 1) / TPB, TPB, 0, stream>>>(
        w_bl1, wt1, w_bl2, wt2, w_d2, wtd2, w_d3, wtd3,
        w_off2, wtoff2, w_off3, wtoff3, w_d1, wtd1, stats1);

    deform1_kernel<<<8 * 25600 / 32, TPB, 0, stream>>>(
        (const unsigned short*)bufC, w_off1, b_off1, wtd1, b_d1,
        pool, w_skip, b_skip, hB);

    conv3x3_mfma_kernel<0><<<800, TPB, 0, stream>>>(
        hB, wt1, hC, stats1, nullptr, invN, zpage);

    conv3x3_mfma_kernel<1><<<800, TPB, 0, stream>>>(
        hC, wt2, hB, stats2, stats1, invN, zpage);

    bn_apply_dual_kernel<<<8 * 400, TPB, 0, stream>>>(
        hB, stats2, out0, hC, 25600, invN);

    offconv_mfma_kernel<<<8 * 6400 / 64, TPB, 0, stream>>>(
        hC, wtoff2, b_off2, A, 160, 160, 80, 80);

    deform_mfma_kernel<64, 1><<<8 * 6400 / 32, TPB, 0, stream>>>(
        hC, A, wtd2, b_d2, out1, hB, 160, 160, 80, 80, 2);

    offconv_mfma_kernel<<<8 * 1600 / 64, TPB, 0, stream>>>(
        hB, wtoff3, b_off3, A, 80, 80, 40, 40);

    deform_mfma_kernel<256, 0><<<8 * 1600 / 32, TPB, 0, stream>>>(
        hB, A, wtd3, b_d3, out2, nullptr, 80, 80, 40, 40, 2);
}

// Round 24
// 205.546 us; speedup vs baseline: 1.1059x; 1.0002x over previous
//
#include <hip/hip_runtime.h>
#include <hip/hip_bf16.h>
#include <math.h>

#define TPB 256

typedef __attribute__((ext_vector_type(8))) short bf16x8_t;
typedef __attribute__((ext_vector_type(4))) float f32x4_t;
typedef __attribute__((ext_vector_type(4))) int i32x4_t;
typedef __attribute__((ext_vector_type(4))) unsigned short u16x4_t;
typedef __attribute__((ext_vector_type(8))) unsigned short u16x8_t;

#if defined(__has_builtin)
#if __has_builtin(__builtin_amdgcn_global_load_lds)
#define HAS_GLOAD_LDS 1
#endif
#endif

static __device__ __forceinline__ float bf16_to_f(unsigned short s) {
    union { unsigned u; float f; } cv;
    cv.u = ((unsigned)s) << 16;
    return cv.f;
}
static __device__ __forceinline__ short f_to_bf16(float v) {
    __hip_bfloat16 h = __float2bfloat16(v);
    return *(short*)&h;
}

// ------------------------------------------------- prep: x NCHW -> x4 NHWC4 bf16 + pool
__global__ void prep_kernel(const float* __restrict__ in,
                            unsigned short* __restrict__ x4,
                            float* __restrict__ pool)
{
    const int HWo = 25600, H = 640, W = 640;
    int idx = blockIdx.x * TPB + threadIdx.x;
    if (idx >= 8 * HWo) return;
    int b = idx / HWo, r = idx % HWo;
    int ho = r / 160, wo = r % 160;
    float s0 = 0.f, s1 = 0.f, s2 = 0.f;
    unsigned short* x4b = x4 + (size_t)b * H * W * 4;
#pragma unroll
    for (int dy = 0; dy < 4; ++dy) {
        int row = ho * 4 + dy;
        size_t base = ((size_t)row * W + wo * 4);
        f32x4_t a0 = *(const f32x4_t*)&in[((size_t)(b * 3 + 0) * H * W) + base];
        f32x4_t a1 = *(const f32x4_t*)&in[((size_t)(b * 3 + 1) * H * W) + base];
        f32x4_t a2 = *(const f32x4_t*)&in[((size_t)(b * 3 + 2) * H * W) + base];
        s0 += a0[0] + a0[1] + a0[2] + a0[3];
        s1 += a1[0] + a1[1] + a1[2] + a1[3];
        s2 += a2[0] + a2[1] + a2[2] + a2[3];
#pragma unroll
        for (int dx = 0; dx < 4; ++dx) {
            u16x4_t v;
            v[0] = (unsigned short)f_to_bf16(a0[dx]);
            v[1] = (unsigned short)f_to_bf16(a1[dx]);
            v[2] = (unsigned short)f_to_bf16(a2[dx]);
            v[3] = 0;
            *(u16x4_t*)&x4b[(base + dx) * 4] = v;
        }
    }
    pool[((size_t)(b * 3 + 0)) * HWo + r] = s0 * (1.0f / 16.0f);
    pool[((size_t)(b * 3 + 1)) * HWo + r] = s1 * (1.0f / 16.0f);
    pool[((size_t)(b * 3 + 2)) * HWo + r] = s2 * (1.0f / 16.0f);
}

// ------------------------------------------------- single repack-everything kernel
static __device__ __forceinline__ void repack_one(
    const float* __restrict__ w, short* __restrict__ wtf,
    int idx, int Oreal, int NFRAG)
{
    int j    = idx & 7;
    int lane = (idx >> 3) & 63;
    int t    = idx >> 9;
    int ocf  = t % NFRAG;
    int kc   = t / NFRAG;
    int oc   = ocf * 16 + (lane & 15);
    int tap  = kc >> 1;
    int ic   = (kc & 1) * 32 + (lane >> 4) * 8 + j;
    float v = 0.f;
    if (oc < Oreal)
        v = w[((size_t)(oc * 64 + ic)) * 9 + tap];
    wtf[idx] = f_to_bf16(v);
}

__global__ void repack_all_kernel(
    const float* __restrict__ w_bl1, short* __restrict__ wt1,
    const float* __restrict__ w_bl2, short* __restrict__ wt2,
    const float* __restrict__ w_d2,  short* __restrict__ wtd2,
    const float* __restrict__ w_d3,  short* __restrict__ wtd3,
    const float* __restrict__ w_off2, short* __restrict__ wtoff2,
    const float* __restrict__ w_off3, short* __restrict__ wtoff3,
    const float* __restrict__ w_d1,  short* __restrict__ wtd1,
    float* __restrict__ stats)
{
    int idx = blockIdx.x * TPB + threadIdx.x;
    if (idx < 36864) { repack_one(w_bl1, wt1, idx, 64, 4); return; }
    idx -= 36864;
    if (idx < 36864) { repack_one(w_bl2, wt2, idx, 64, 4); return; }
    idx -= 36864;
    if (idx < 36864) { repack_one(w_d2, wtd2, idx, 64, 4); return; }
    idx -= 36864;
    if (idx < 147456) { repack_one(w_d3, wtd3, idx, 256, 16); return; }
    idx -= 147456;
    if (idx < 18432) { repack_one(w_off2, wtoff2, idx, 18, 2); return; }
    idx -= 18432;
    if (idx < 18432) { repack_one(w_off3, wtoff3, idx, 18, 2); return; }
    idx -= 18432;
    if (idx < 2048) {
        int j = idx & 7, lane = (idx >> 3) & 63, ocf = idx >> 9;
        int oc = ocf * 16 + (lane & 15);
        int k  = (lane >> 4) * 8 + j;
        float v = 0.f;
        if (k < 27) v = w_d1[(size_t)oc * 27 + k];
        wtd1[idx] = f_to_bf16(v);
        return;
    }
    idx -= 2048;
    if (idx < 2560) stats[idx] = 0.f;
}

// ------------------------------------------------- MFMA conv 3x3 (64->64, s1)
template <int NORM>
__global__ __launch_bounds__(256, 2) void conv3x3_mfma_kernel(
    const short* __restrict__ xh,
    const short* __restrict__ wt,
    short* __restrict__ outh,
    float* __restrict__ stats,
    const float* __restrict__ stats_in,
    float invN,
    const float* __restrict__ zp)
{
    __shared__ short tile[2816 * 8];
    __shared__ float sstat[128];
    __shared__ float sm[64], sr[64];
    const int H = 160, W = 160, HW = 25600;
    int blk = blockIdx.x;
    int b  = blk / 100;
    int r  = blk % 100;
    int y0 = (r / 10) * 16;
    int x0 = (r % 10) * 16;
    const int tid = threadIdx.x;
    const short* inb = xh + (size_t)b * HW * 64;

    if (tid < 128) sstat[tid] = 0.f;
    if (NORM) {
        if (tid < 64) {
            float s = 0.f, s2 = 0.f;
#pragma unroll
            for (int k = 0; k < 8; ++k) {
                s  += stats_in[k * 128 + tid];
                s2 += stats_in[k * 128 + 64 + tid];
            }
            float mean = s * invN;
            float var  = s2 * invN - mean * mean;
            sm[tid] = mean;
            sr[tid] = rsqrtf(var + 1e-5f);
        }
        __syncthreads();
    }

    if (NORM == 0) {
#ifdef HAS_GLOAD_LDS
#pragma unroll
        for (int it = 0; it < 11; ++it) {
            int item = it * 256 + tid;
            int c8  = item & 7;
            int pix = item >> 3;
            int row = pix / 18;
            int col = pix - row * 18;
            int y = y0 + row - 1;
            int x = x0 + col - 1;
            bool ok = (pix < 324) & (y >= 0) & (y < H) & (x >= 0) & (x < W);
            int cs = c8 ^ (col & 7);
            const short* src = ok
                ? &inb[((size_t)y * W + x) * 64 + (cs << 3)]
                : (const short*)zp;
            __builtin_amdgcn_global_load_lds(
                (const __attribute__((address_space(1))) unsigned int*)src,
                (__attribute__((address_space(3))) unsigned int*)
                    &tile[(it * 256 + (tid & 192)) * 8],
                16, 0, 0);
        }
#else
#pragma unroll
        for (int it = 0; it < 11; ++it) {
            int item = it * 256 + tid;
            int c8  = item & 7;
            int pix = item >> 3;
            int row = pix / 18;
            int col = pix - row * 18;
            int y = y0 + row - 1;
            int x = x0 + col - 1;
            bool ok = (pix < 324) & (y >= 0) & (y < H) & (x >= 0) & (x < W);
            int cs = c8 ^ (col & 7);
            const short* src = ok
                ? &inb[((size_t)y * W + x) * 64 + (cs << 3)]
                : (const short*)zp;
            *(bf16x8_t*)&tile[item * 8] = *(const bf16x8_t*)src;
        }
#endif
    } else {
#pragma unroll
        for (int it = 0; it < 11; ++it) {
            int item = it * 256 + tid;
            int c8  = item & 7;
            int pix = item >> 3;
            int row = pix / 18;
            int col = pix - row * 18;
            int y = y0 + row - 1;
            int x = x0 + col - 1;
            bool ok = (pix < 324) & (y >= 0) & (y < H) & (x >= 0) & (x < W);
            int cs = c8 ^ (col & 7);
            const short* src = ok
                ? &inb[((size_t)y * W + x) * 64 + (cs << 3)]
                : (const short*)zp;
            bf16x8_t v = *(const bf16x8_t*)src;
            int cs8 = cs << 3;
            bf16x8_t o;
#pragma unroll
            for (int j = 0; j < 8; ++j) {
                float f = (bf16_to_f((unsigned short)v[j]) - sm[cs8 + j]) * sr[cs8 + j];
                f = f > 0.f ? f : 0.f;
                o[j] = ok ? f_to_bf16(f) : (short)0;
            }
            *(bf16x8_t*)&tile[item * 8] = o;
        }
    }
    __syncthreads();

    const int wv  = tid >> 6;
    const int l   = tid & 63;
    const int l15 = l & 15;
    const int lg  = l >> 4;

    f32x4_t acc[4][4];
#pragma unroll
    for (int i = 0; i < 4; ++i)
#pragma unroll
        for (int j = 0; j < 4; ++j)
            acc[i][j] = (f32x4_t){0.f, 0.f, 0.f, 0.f};

    bf16x8_t bfp[2][4], afp[2][4];
#pragma unroll
    for (int nf = 0; nf < 4; ++nf)
        bfp[0][nf] = *(const bf16x8_t*)(wt + (((size_t)(0 * 4 + nf)) * 64 + l) * 8);
    {
        int colr = l15;
        int chunk = lg ^ (colr & 7);
#pragma unroll
        for (int mf = 0; mf < 4; ++mf)
            afp[0][mf] = *(const bf16x8_t*)&tile[((wv * 4 + mf) * 18 + colr) * 64 + chunk * 8];
    }
#pragma unroll
    for (int kc = 0; kc < 18; ++kc) {
        const int cur = kc & 1, nxt = cur ^ 1;
        if (kc + 1 < 18) {
            int kn = kc + 1;
#pragma unroll
            for (int nf = 0; nf < 4; ++nf)
                bfp[nxt][nf] = *(const bf16x8_t*)(wt + (((size_t)(kn * 4 + nf)) * 64 + l) * 8);
            int tap = kn >> 1;
            int dy = tap / 3, dx = tap % 3;
            int colr = l15 + dx;
            int chunk = (((kn & 1) << 2) + lg) ^ (colr & 7);
#pragma unroll
            for (int mf = 0; mf < 4; ++mf)
                afp[nxt][mf] = *(const bf16x8_t*)&tile[((wv * 4 + mf + dy) * 18 + colr) * 64 + chunk * 8];
        }
#pragma unroll
        for (int mf = 0; mf < 4; ++mf)
#pragma unroll
            for (int nf = 0; nf < 4; ++nf)
                acc[mf][nf] = __builtin_amdgcn_mfma_f32_16x16x32_bf16(
                    afp[cur][mf], bfp[cur][nf], acc[mf][nf], 0, 0, 0);
    }

    __syncthreads();
#pragma unroll
    for (int mf = 0; mf < 4; ++mf) {
        int py = wv * 4 + mf;
#pragma unroll
        for (int nf = 0; nf < 4; ++nf) {
            int oc = nf * 16 + l15;
#pragma unroll
            for (int k = 0; k < 4; ++k)
                tile[((py * 16) + lg * 4 + k) * 64 + oc] = f_to_bf16(acc[mf][nf][k]);
        }
    }
    __syncthreads();
    short* outb = outh + (size_t)b * HW * 64;
#pragma unroll
    for (int j = 0; j < 8; ++j) {
        int item = j * 256 + tid;
        int c8  = item & 7;
        int pix = item >> 3;
        int py  = pix >> 4, px = pix & 15;
        *(bf16x8_t*)&outb[((size_t)(y0 + py) * W + x0 + px) * 64 + c8 * 8] =
            *(bf16x8_t*)&tile[pix * 64 + c8 * 8];
    }

#pragma unroll
    for (int nf = 0; nf < 4; ++nf) {
        float s = 0.f, s2 = 0.f;
#pragma unroll
        for (int mf = 0; mf < 4; ++mf)
#pragma unroll
            for (int k = 0; k < 4; ++k) {
                float v = acc[mf][nf][k];
                s += v; s2 += v * v;
            }
        s  += __shfl_xor(s, 16, 64);  s  += __shfl_xor(s, 32, 64);
        s2 += __shfl_xor(s2, 16, 64); s2 += __shfl_xor(s2, 32, 64);
        if (lg == 0) {
            int oc = nf * 16 + l15;
            atomicAdd(&sstat[oc], s);
            atomicAdd(&sstat[64 + oc], s2);
        }
    }
    __syncthreads();
    float* st = stats + (size_t)(blockIdx.x & 7) * 128;
    if (tid < 128) atomicAdd(&st[tid], sstat[tid]);
}

// ------------------------------------------------- BN apply dual
__global__ void bn_apply_dual_kernel(const short* __restrict__ in,
                                     const float* __restrict__ stats,
                                     float* __restrict__ out,
                                     short* __restrict__ outh,
                                     int HW, float invN)
{
    __shared__ float ftile[64][65];
    __shared__ float sm[64], sr[64];
    int nchunks = HW >> 6;
    int b  = blockIdx.x / nchunks;
    int p0 = (blockIdx.x % nchunks) << 6;
    int tid = threadIdx.x;
    if (tid < 64) {
        float s = 0.f, s2 = 0.f;
#pragma unroll
        for (int k = 0; k < 8; ++k) {
            s  += stats[k * 128 + tid];
            s2 += stats[k * 128 + 64 + tid];
        }
        float mean = s * invN;
        float var  = s2 * invN - mean * mean;
        sm[tid] = mean;
        sr[tid] = rsqrtf(var + 1e-5f);
    }
    __syncthreads();
#pragma unroll
    for (int it = 0; it < 2; ++it) {
        int item = it * 256 + tid;
        int p = item >> 3, c0 = (item & 7) * 8;
        size_t gi = ((size_t)(b * HW + p0 + p)) * 64 + c0;
        bf16x8_t v = *(const bf16x8_t*)&in[gi];
        bf16x8_t o;
#pragma unroll
        for (int j = 0; j < 8; ++j) {
            float f = (bf16_to_f((unsigned short)v[j]) - sm[c0 + j]) * sr[c0 + j];
            f = f > 0.f ? f : 0.f;
            ftile[p][c0 + j] = f;
            o[j] = f_to_bf16(f);
        }
        *(bf16x8_t*)&outh[gi] = o;
    }
    __syncthreads();
#pragma unroll
    for (int rep = 0; rep < 16; ++rep) {
        int item = rep * 256 + tid;
        int c = item >> 6, p = item & 63;
        out[((size_t)b * 64 + c) * HW + p0 + p] = ftile[p][c];
    }
}

// ------------------------------------------------- offset2/3: MFMA conv, N=18
__global__ __launch_bounds__(256, 1) void offconv_mfma_kernel(
    const short* __restrict__ xh,
    const short* __restrict__ wt,
    const float* __restrict__ bias,
    float* __restrict__ out,
    int H, int W, int Ho, int Wo)
{
    const int HW = Ho * Wo;
    const int tid = threadIdx.x;
    const int wv = tid >> 6, l = tid & 63;
    const int l15 = l & 15, lg = l >> 4;
    const int pix0 = blockIdx.x * 64 + wv * 16;
    const int b = pix0 / HW;
    const int r0 = pix0 - b * HW;

    int rp = r0 + l15;
    int ho = rp / Wo, wo = rp % Wo;
    const short* xb = xh + (size_t)b * H * W * 64;

    f32x4_t acc[2];
    acc[0] = (f32x4_t){0.f, 0.f, 0.f, 0.f};
    acc[1] = (f32x4_t){0.f, 0.f, 0.f, 0.f};

#pragma unroll 2
    for (int kc = 0; kc < 18; ++kc) {
        int tap = kc >> 1;
        int iy = ho * 2 - 1 + tap / 3;
        int ix = wo * 2 - 1 + tap % 3;
        bf16x8_t af = {};
        if (iy >= 0 && iy < H && ix >= 0 && ix < W)
            af = *(const bf16x8_t*)&xb[((size_t)iy * W + ix) * 64
                                       + (kc & 1) * 32 + lg * 8];
#pragma unroll
        for (int nf = 0; nf < 2; ++nf) {
            bf16x8_t bf = *(const bf16x8_t*)(wt + (((size_t)(kc * 2 + nf)) * 64 + l) * 8);
            acc[nf] = __builtin_amdgcn_mfma_f32_16x16x32_bf16(af, bf, acc[nf], 0, 0, 0);
        }
    }

#pragma unroll
    for (int nf = 0; nf < 2; ++nf) {
        int oc = nf * 16 + l15;
        if (oc < 18) {
            float bv = bias[oc];
            f32x4_t v = acc[nf];
            v[0] += bv; v[1] += bv; v[2] += bv; v[3] += bv;
            *(f32x4_t*)&out[((size_t)(b * 18 + oc)) * HW + r0 + lg * 4] = v;
        }
    }
}

// ------------------------------------------------- deform1: fused offset1 +
// deform (C=3, MFMA MAC) + skip; x4 is bf16 NHWC4
__global__ __launch_bounds__(256, 1) void deform1_kernel(
    const unsigned short* __restrict__ x4,
    const float* __restrict__ wof,
    const float* __restrict__ bof,
    const short* __restrict__ wtd1,
    const float* __restrict__ bias,
    const float* __restrict__ pool,
    const float* __restrict__ wsk,
    const float* __restrict__ bsk,
    short* __restrict__ outh)
{
    const int H = 640, W = 640, Ho = 160, Wo = 160, HW = 25600;
    constexpr int P = 32;
    __shared__ float xtap[P * 9][4];
    __shared__ float swof[486];
    __shared__ float sbof[18];
    __shared__ float spool[3][P];
    __shared__ float off1[P][18];
    __shared__ alignas(16) short sampb[P][40];
    __shared__ int   sidx[P * 9][4];
    __shared__ float swt[P * 9][4];
    const int tid = threadIdx.x;
    const int pix0 = blockIdx.x * P;
    const int b = pix0 / HW;
    const int r0 = pix0 - b * HW;
    const unsigned short* xb = x4 + (size_t)b * H * W * 4;

    for (int item = tid; item < P * 9; item += TPB) {
        int p = item / 9, tap = item % 9;
        int r = r0 + p, ho = r / Wo, wo = r % Wo;
        int iy = ho * 4 - 1 + tap / 3;
        int ix = wo * 4 - 1 + tap % 3;
        f32x4_t s = (f32x4_t){0.f, 0.f, 0.f, 0.f};
        if (iy >= 0 && iy < H && ix >= 0 && ix < W) {
            u16x4_t u = *(const u16x4_t*)&xb[((size_t)iy * W + ix) * 4];
            s[0] = bf16_to_f(u[0]);
            s[1] = bf16_to_f(u[1]);
            s[2] = bf16_to_f(u[2]);
        }
        *(f32x4_t*)xtap[item] = s;
    }
    for (int i = tid; i < P * 40; i += TPB) ((short*)sampb)[i] = 0;
    for (int i = tid; i < 96; i += TPB) {
        int c = i >> 5, p = i & 31;
        spool[c][p] = pool[((size_t)(b * 3 + c)) * HW + r0 + p];
    }
    for (int item = tid; item < 486; item += TPB) swof[item] = wof[item];
    if (tid < 18) sbof[tid] = bof[tid];
    __syncthreads();

    for (int item = tid; item < P * 18; item += TPB) {
        int p = item / 18, o = item % 18;
        float acc = sbof[o];
#pragma unroll
        for (int tap = 0; tap < 9; ++tap) {
            const float* xt = xtap[p * 9 + tap];
#pragma unroll
            for (int c = 0; c < 3; ++c)
                acc += xt[c] * swof[(o * 3 + c) * 9 + tap];
        }
        off1[p][o] = acc;
    }
    __syncthreads();

    for (int item = tid; item < P * 9; item += TPB) {
        int p = item / 9, tap = item % 9;
        int r = r0 + p, ho = r / Wo, wo = r % Wo;
        float dy = off1[p][2 * tap];
        float dx = off1[p][2 * tap + 1];
        float ys = (float)(ho * 4 - 1 + tap / 3) + dy;
        float xs = (float)(wo * 4 - 1 + tap % 3) + dx;
        float y0f = floorf(ys), x0f = floorf(xs);
        float fy = ys - y0f, fx = xs - x0f;
        int y0 = (int)y0f, x0 = (int)x0f;
        float wts[4] = {(1.f - fy) * (1.f - fx), (1.f - fy) * fx,
                        fy * (1.f - fx),          fy * fx};
#pragma unroll
        for (int j = 0; j < 4; ++j) {
            int iy = y0 + (j >> 1), ix = x0 + (j & 1);
            bool v = (iy >= 0) && (iy < H) && (ix >= 0) && (ix < W);
            sidx[item][j] = v ? (iy * W + ix) : 0;
            swt[item][j]  = v ? wts[j] : 0.f;
        }
    }
    __syncthreads();

    for (int item = tid; item < P * 9; item += TPB) {
        int p = item / 9, tap = item % 9;
        i32x4_t id4 = *(const i32x4_t*)sidx[item];
        f32x4_t w4  = *(const f32x4_t*)swt[item];
        u16x4_t a0 = *(const u16x4_t*)&xb[(size_t)(unsigned)id4[0] * 4];
        u16x4_t a1 = *(const u16x4_t*)&xb[(size_t)(unsigned)id4[1] * 4];
        u16x4_t a2 = *(const u16x4_t*)&xb[(size_t)(unsigned)id4[2] * 4];
        u16x4_t a3 = *(const u16x4_t*)&xb[(size_t)(unsigned)id4[3] * 4];
        sampb[p][0 * 9 + tap] = f_to_bf16(
            w4[0]*bf16_to_f(a0[0]) + w4[1]*bf16_to_f(a1[0])
          + w4[2]*bf16_to_f(a2[0]) + w4[3]*bf16_to_f(a3[0]));
        sampb[p][1 * 9 + tap] = f_to_bf16(
            w4[0]*bf16_to_f(a0[1]) + w4[1]*bf16_to_f(a1[1])
          + w4[2]*bf16_to_f(a2[1]) + w4[3]*bf16_to_f(a3[1]));
        sampb[p][2 * 9 + tap] = f_to_bf16(
            w4[0]*bf16_to_f(a0[2]) + w4[1]*bf16_to_f(a1[2])
          + w4[2]*bf16_to_f(a2[2]) + w4[3]*bf16_to_f(a3[2]));
    }
    __syncthreads();

    const int wv = tid >> 6;
    const int l  = tid & 63;
    const int l15 = l & 15, lg = l >> 4;
    bf16x8_t bf  = *(const bf16x8_t*)(wtd1 + (((size_t)wv * 64 + l)) * 8);
    bf16x8_t af0 = *(const bf16x8_t*)&sampb[l15][lg * 8];
    bf16x8_t af1 = *(const bf16x8_t*)&sampb[l15 + 16][lg * 8];
    f32x4_t z = (f32x4_t){0.f, 0.f, 0.f, 0.f};
    f32x4_t acc0 = __builtin_amdgcn_mfma_f32_16x16x32_bf16(af0, bf, z, 0, 0, 0);
    f32x4_t acc1 = __builtin_amdgcn_mfma_f32_16x16x32_bf16(af1, bf, z, 0, 0, 0);

    int oc = wv * 16 + l15;
    float bb = bias[oc] + bsk[oc];
    float w0 = wsk[oc * 3 + 0], w1 = wsk[oc * 3 + 1], w2 = wsk[oc * 3 + 2];
    short* otile = (short*)xtap;
    __syncthreads();
#pragma unroll
    for (int mf = 0; mf < 2; ++mf) {
        f32x4_t a = mf ? acc1 : acc0;
#pragma unroll
        for (int k = 0; k < 4; ++k) {
            int px = mf * 16 + lg * 4 + k;
            float sv = w0 * spool[0][px] + w1 * spool[1][px] + w2 * spool[2][px];
            otile[px * 64 + oc] = f_to_bf16(a[k] + bb + sv);
        }
    }
    __syncthreads();
    {
        int c8 = tid & 7, px = tid >> 3;
        *(bf16x8_t*)&outh[((size_t)(b * HW + r0 + px)) * 64 + c8 * 8] =
            *(bf16x8_t*)&otile[px * 64 + c8 * 8];
    }
}

// ------------------------------------------------- deform MFMA: C=64 -> O
template <int O, int DUAL>
__global__ __launch_bounds__(256, 1) void deform_mfma_kernel(
    const short* __restrict__ xh,
    const float* __restrict__ off,
    const short* __restrict__ wt,
    const float* __restrict__ bias,
    float* __restrict__ out,
    short* __restrict__ outh,
    int H, int W, int Ho, int Wo, int stride)
{
    constexpr int NF = O / 64;
    constexpr int NFRAG = O / 16;
    constexpr int P  = 32;
    __shared__ alignas(16) short samp[P * 576];
    __shared__ int   sidx[P * 9][4];
    __shared__ float swt[P * 9][4];

    const int tid = threadIdx.x;
    const int HW = Ho * Wo;
    const int pix0 = blockIdx.x * P;
    const int b = pix0 / HW;
    const int r0 = pix0 - b * HW;

    for (int item = tid; item < P * 9; item += TPB) {
        int p = item / 9, tap = item % 9;
        int r = r0 + p, ho = r / Wo, wo = r % Wo;
        float dy = off[((size_t)(b * 18 + 2 * tap) * Ho + ho) * Wo + wo];
        float dx = off[((size_t)(b * 18 + 2 * tap + 1) * Ho + ho) * Wo + wo];
        float ys = (float)(ho * stride - 1 + tap / 3) + dy;
        float xs = (float)(wo * stride - 1 + tap % 3) + dx;
        float y0f = floorf(ys), x0f = floorf(xs);
        float fy = ys - y0f, fx = xs - x0f;
        int y0 = (int)y0f, x0 = (int)x0f;
        float wts[4] = {(1.f - fy) * (1.f - fx), (1.f - fy) * fx,
                        fy * (1.f - fx),          fy * fx};
#pragma unroll
        for (int j = 0; j < 4; ++j) {
            int iy = y0 + (j >> 1), ix = x0 + (j & 1);
            bool v = (iy >= 0) && (iy < H) && (ix >= 0) && (ix < W);
            sidx[item][j] = v ? (iy * W + ix) : 0;
            swt[item][j]  = v ? wts[j] : 0.f;
        }
    }
    __syncthreads();

    {
        const int p  = tid >> 3;
        const int ic = (tid & 7) * 8;
        const int swc = (ic >> 3) ^ (p & 7);
        const short* xb = xh + (size_t)b * H * W * 64;
#pragma unroll 3
        for (int tap = 0; tap < 9; ++tap) {
            int e = p * 9 + tap;
            i32x4_t id4 = *(const i32x4_t*)sidx[e];
            f32x4_t w4  = *(const f32x4_t*)swt[e];
            u16x8_t u0 = *(const u16x8_t*)&xb[(size_t)(unsigned)id4[0] * 64 + ic];
            u16x8_t u1 = *(const u16x8_t*)&xb[(size_t)(unsigned)id4[1] * 64 + ic];
            u16x8_t u2 = *(const u16x8_t*)&xb[(size_t)(unsigned)id4[2] * 64 + ic];
            u16x8_t u3 = *(const u16x8_t*)&xb[(size_t)(unsigned)id4[3] * 64 + ic];
            bf16x8_t o;
#pragma unroll
            for (int j = 0; j < 8; ++j) {
                float v = w4[0]*bf16_to_f(u0[j]) + w4[1]*bf16_to_f(u1[j])
                        + w4[2]*bf16_to_f(u2[j]) + w4[3]*bf16_to_f(u3[j]);
                o[j] = f_to_bf16(v);
            }
            *(bf16x8_t*)&samp[p * 576 + (tap * 8 + swc) * 8] = o;
        }
    }
    __syncthreads();

    const int wv = tid >> 6;
    const int l  = tid & 63;
    const int l15 = l & 15, lg = l >> 4;
    f32x4_t acc[2][NF];
#pragma unroll
    for (int mf = 0; mf < 2; ++mf)
#pragma unroll
        for (int nf = 0; nf < NF; ++nf)
            acc[mf][nf] = (f32x4_t){0.f, 0.f, 0.f, 0.f};

#pragma unroll 2
    for (int kc = 0; kc < 18; ++kc) {
        int tap = kc >> 1;
        int low = (((kc & 1) << 2) | lg) ^ (l15 & 7);
        bf16x8_t af0 = *(const bf16x8_t*)&samp[l15 * 576 + (tap * 8 + low) * 8];
        bf16x8_t af1 = *(const bf16x8_t*)&samp[(l15 + 16) * 576 + (tap * 8 + low) * 8];
#pragma unroll
        for (int nf = 0; nf < NF; ++nf) {
            int ocf = wv * NF + nf;
            bf16x8_t bf = *(const bf16x8_t*)(wt + (((size_t)(kc * NFRAG + ocf)) * 64 + l) * 8);
            acc[0][nf] = __builtin_amdgcn_mfma_f32_16x16x32_bf16(af0, bf, acc[0][nf], 0, 0, 0);
            acc[1][nf] = __builtin_amdgcn_mfma_f32_16x16x32_bf16(af1, bf, acc[1][nf], 0, 0, 0);
        }
    }

#pragma unroll
    for (int mf = 0; mf < 2; ++mf)
#pragma unroll
        for (int nf = 0; nf < NF; ++nf) {
            int oc = (wv * NF + nf) * 16 + l15;
            float bv = bias[oc];
            f32x4_t v = acc[mf][nf];
            v[0] += bv; v[1] += bv; v[2] += bv; v[3] += bv;
            acc[mf][nf] = v;
            *(f32x4_t*)&out[((size_t)(b * O + oc)) * HW + r0 + mf * 16 + lg * 4] = v;
        }

    if (DUAL) {
        __syncthreads();
        short* otile = samp;
#pragma unroll
        for (int mf = 0; mf < 2; ++mf) {
            int oc = wv * 16 + l15;
#pragma unroll
            for (int k = 0; k < 4; ++k) {
                int px = mf * 16 + lg * 4 + k;
                otile[px * 64 + oc] = f_to_bf16(acc[mf][0][k]);
            }
        }
        __syncthreads();
        int c8 = tid & 7, px = tid >> 3;
        *(bf16x8_t*)&outh[((size_t)(b * HW + r0 + px)) * 64 + c8 * 8] =
            *(bf16x8_t*)&otile[px * 64 + c8 * 8];
    }
}

// ---------------------------------------------------------------- launch
extern "C" void kernel_launch(void* const* d_in, const int* in_sizes, int n_in,
                              void* d_out, int out_size, void* d_ws, size_t ws_size,
                              hipStream_t stream)
{
    const float* x      = (const float*)d_in[0];
    const float* w_off1 = (const float*)d_in[1];
    const float* b_off1 = (const float*)d_in[2];
    const float* w_d1   = (const float*)d_in[3];
    const float* b_d1   = (const float*)d_in[4];
    const float* w_skip = (const float*)d_in[5];
    const float* b_skip = (const float*)d_in[6];
    const float* w_bl1  = (const float*)d_in[7];
    const float* w_bl2  = (const float*)d_in[8];
    const float* w_off2 = (const float*)d_in[9];
    const float* b_off2 = (const float*)d_in[10];
    const float* w_d2   = (const float*)d_in[11];
    const float* b_d2   = (const float*)d_in[12];
    const float* w_off3 = (const float*)d_in[13];
    const float* b_off3 = (const float*)d_in[14];
    const float* w_d3   = (const float*)d_in[15];
    const float* b_d3   = (const float*)d_in[16];

    const int B = 8;
    float* A     = (float*)d_ws;
    float* bufB  = A + 3686400;
    float* bufC  = bufB + 13107200;

    short* hB   = (short*)bufB;
    short* hC   = (short*)bufC;
    float* pool = bufB + 8000000;

    short* wt1    = (short*)(A + 1000000);
    short* wt2    = wt1 + 18 * 4 * 512;
    short* wtd2   = (short*)(A + 1500000);
    short* wtd3   = (short*)(A + 1550000);
    short* wtoff2 = (short*)(A + 1700000);
    short* wtoff3 = (short*)(A + 1712000);
    short* wtd1   = (short*)(A + 1750000);
    float* stats1 = A + 1800000;
    float* stats2 = stats1 + 1024;
    float* zpage  = stats1 + 2048;

    float* out0 = (float*)d_out;
    float* out1 = out0 + 13107200;
    float* out2 = out1 + 3276800;

    const float invN = 1.0f / (B * 25600);

    prep_kernel<<<(8 * 25600 + TPB - 1) / TPB, TPB, 0, stream>>>(
        x, (unsigned short*)bufC, pool);

    repack_all_kernel<<<(299520 + TPB - 1) / TPB, TPB, 0, stream>>>(
        w_bl1, wt1, w_bl2, wt2, w_d2, wtd2, w_d3, wtd3,
        w_off2, wtoff2, w_off3, wtoff3, w_d1, wtd1, stats1);

    deform1_kernel<<<8 * 25600 / 32, TPB, 0, stream>>>(
        (const unsigned short*)bufC, w_off1, b_off1, wtd1, b_d1,
        pool, w_skip, b_skip, hB);

    conv3x3_mfma_kernel<0><<<800, TPB, 0, stream>>>(
        hB, wt1, hC, stats1, nullptr, invN, zpage);

    conv3x3_mfma_kernel<1><<<800, TPB, 0, stream>>>(
        hC, wt2, hB, stats2, stats1, invN, zpage);

    bn_apply_dual_kernel<<<8 * 400, TPB, 0, stream>>>(
        hB, stats2, out0, hC, 25600, invN);

    offconv_mfma_kernel<<<8 * 6400 / 64, TPB, 0, stream>>>(
        hC, wtoff2, b_off2, A, 160, 160, 80, 80);

    deform_mfma_kernel<64, 1><<<8 * 6400 / 32, TPB, 0, stream>>>(
        hC, A, wtd2, b_d2, out1, hB, 160, 160, 80, 80, 2);

    offconv_mfma_kernel<<<8 * 1600 / 64, TPB, 0, stream>>>(
        hB, wtoff3, b_off3, A, 80, 80, 40, 40);

    deform_mfma_kernel<256, 0><<<8 * 1600 / 32, TPB, 0, stream>>>(
        hB, A, wtd3, b_d3, out2, nullptr, 80, 80, 40, 40, 2);
}